// Round 1
// baseline (340.164 us; speedup 1.0000x reference)
//
#include <hip/hip_runtime.h>

#define NEGF -1e30f
typedef unsigned int uint32;

static constexpr int Bb = 64, Tt = 2048, Vv = 256, Uu = 256;
// S = 2*U+1 = 513 states; lane l owns states 8l..8l+7 (+512 on lane 63).
// Ebs layout (per batch, 2048 floats): Ebs[i] = blank[i+1] for i=0..2046,
// Ebs[2047] = blank[0].

__device__ __forceinline__ unsigned short f2bf(float f) {    // RNE, no NaN inputs
  uint32 u = __builtin_bit_cast(uint32, f);
  u += 0x7fffu + ((u >> 16) & 1u);
  return (unsigned short)(u >> 16);
}
__device__ __forceinline__ float bf2f_lo(uint32 p) { return __builtin_bit_cast(float, p << 16); }
__device__ __forceinline__ float bf2f_hi(uint32 p) { return __builtin_bit_cast(float, p & 0xffff0000u); }

// DPP cross-lane, gfx9-family wave-level shifts (1 VALU op, no LDS):
// wave_shr:1 (0x138): lane l <- lane l-1; lane 0 keeps `old` (bound_ctrl=0).
// wave_shl:1 (0x130): lane l <- lane l+1; lane 63 keeps `old`.
__device__ __forceinline__ float dpp_shr1(float old, float src) {
  return __builtin_bit_cast(float, __builtin_amdgcn_update_dpp(
      __builtin_bit_cast(int, old), __builtin_bit_cast(int, src), 0x138, 0xF, 0xF, false));
}
__device__ __forceinline__ float dpp_shl1(float old, float src) {
  return __builtin_bit_cast(float, __builtin_amdgcn_update_dpp(
      __builtin_bit_cast(int, old), __builtin_bit_cast(int, src), 0x130, 0xF, 0xF, false));
}

// ---------------------------------------------------------------------------
// Kernel A: one streaming pass over logits; 8 rows in flight per wave.
//   - acc[0] += sum of logsumexp over valid frames
//   - E[b][t][u] = bf16(logits[b][t][targets[b][u]]), t < L only
//   - Ebs shifted-blank array
// (unchanged from baseline)
// ---------------------------------------------------------------------------
__global__ __launch_bounds__(256) void gather_lse_kernel(
    const float* __restrict__ logits, const int* __restrict__ targets,
    const int* __restrict__ llen, float* __restrict__ acc,
    float* __restrict__ Ebs, unsigned short* __restrict__ E) {
  __shared__ __align__(16) float buf[4][8][Vv];   // 32 KB
  __shared__ float wpart[4];
  const int b = blockIdx.x >> 5;
  const int c = blockIdx.x & 31;
  const int w = threadIdx.x >> 6;
  const int lane = threadIdx.x & 63;
  const int L = llen[b];
  const int4 lb = reinterpret_cast<const int4*>(targets + (b << 8))[lane];
  const float* __restrict__ lgb = logits + (size_t)b * (Tt * Vv);
  float lse_local = 0.f;
#pragma unroll
  for (int k = 0; k < 2; ++k) {
    const int tbase = (c << 6) + (k << 5) + w;    // rows tbase + 4j, j=0..7
    if (tbase >= L) break;                        // wave-uniform
    float4 v[8];
#pragma unroll
    for (int j = 0; j < 8; ++j)
      v[j] = reinterpret_cast<const float4*>(lgb + (size_t)(tbase + 4 * j) * Vv)[lane];
    float s[8];
#pragma unroll
    for (int j = 0; j < 8; ++j)
      s[j] = __expf(v[j].x) + __expf(v[j].y) + __expf(v[j].z) + __expf(v[j].w);
#pragma unroll
    for (int off = 32; off; off >>= 1) {
#pragma unroll
      for (int j = 0; j < 8; ++j) s[j] += __shfl_down(s[j], off);
    }
#pragma unroll
    for (int j = 0; j < 8; ++j)
      reinterpret_cast<float4*>(&buf[w][j][0])[lane] = v[j];
#pragma unroll
    for (int j = 0; j < 8; ++j) {                 // intra-wave DS ordering
      const int t = tbase + 4 * j;
      const bool val = t < L;
      ushort4 o;
      o.x = f2bf(buf[w][j][lb.x]); o.y = f2bf(buf[w][j][lb.y]);
      o.z = f2bf(buf[w][j][lb.z]); o.w = f2bf(buf[w][j][lb.w]);
      if (val)
        reinterpret_cast<ushort4*>(E + ((size_t)((b << 11) + t)) * Vv)[lane] = o;
      if ((lane == 0) & val) {
        lse_local += __logf(s[j]);
        Ebs[(b << 11) + ((t == 0) ? 2047 : t - 1)] = v[j].x;   // row[0] = blank
      }
    }
  }
  if (lane == 0) wpart[w] = lse_local;
  __syncthreads();
  if (threadIdx.x == 0)
    atomicAdd(acc, wpart[0] + wpart[1] + wpart[2] + wpart[3]);
}

// ---------------------------------------------------------------------------
// Kernel B: bidirectional max-plus Viterbi, ONE wave per batch (R8).
// R7 ran fwd/bwd as 2 waves on 2 different SIMDs: each SIMD held exactly one
// wave, so the ~130 cyc/step of dep-chain/waitcnt stall was fully exposed
// (190 cyc/step measured vs ~60 cyc issue). R8 fuses both independent chains
// into one wave, interleaved per-step in the same basic block: the second
// chain's instructions fill the first chain's stall slots. Ring prefetch PG
// drops 8->4 per direction (same 96 ring VGPRs total as R7).
//   fwd: alpha forward t=0..M (em-inclusive), M=(L-2)>>1  (f0..f8)
//   bwd: beta backward t=L-1..M+1                          (h0..h8)
//   merge: acc[0] -= max_s alpha[M][s] + max(beta[s], beta[s+1], skip? beta[s+2])
// ---------------------------------------------------------------------------
#define PG 4
__global__ __launch_bounds__(64) void viterbi_kernel(
    const unsigned short* __restrict__ E, const float* __restrict__ Ebs,
    const int* __restrict__ targets, const int* __restrict__ llen,
    const int* __restrict__ tlen, float* __restrict__ acc) {
  __shared__ __align__(16) float LB[2048];   // blanks (shifted layout), 8 KB
  __shared__ float Bt[520];
  const int b = blockIdx.x;
  const int lane = threadIdx.x;              // 64-thread block == 1 wave
  const int L = llen[b];
  const int tl = tlen[b];
  const int M = (L - 2) >> 1;
  const int4 lb = reinterpret_cast<const int4*>(targets + (b << 8))[lane];
  const uint2* __restrict__ Erow = reinterpret_cast<const uint2*>(E) + ((size_t)(b << 11) << 6);
  const float* __restrict__ Ebb = Ebs + (b << 11);

  // cooperative blank preload: 2048 floats
  {
    const float4* src = reinterpret_cast<const float4*>(Ebb);
    float4* dst = reinterpret_cast<float4*>(LB);
    for (int i = lane; i < 512; i += 64) dst[i] = src[i];
  }
  __syncthreads();

  // skip masks (time-invariant). Note kb0..kb2 of the bwd chain coincide with
  // sk1..sk3 of the fwd chain; only kb3 is new.
  const int prevw = __shfl_up(lb.w, 1);
  const bool sk0 = (lane != 0) && (lb.x != prevw);
  const bool sk1 = (lb.y != lb.x);
  const bool sk2 = (lb.z != lb.y);
  const bool sk3 = (lb.w != lb.z);
  const int nlabx = __shfl_down(lb.x, 1);
  const bool kb0 = sk1;
  const bool kb1 = sk2;
  const bool kb2 = sk3;
  const bool kb3 = (lane < 63) && (nlabx != lb.w);

  // ---- forward state init ----
  float f0 = NEGF, f1 = NEGF, f2 = NEGF, f3 = NEGF, f4 = NEGF,
        f5 = NEGF, f6 = NEGF, f7 = NEGF, f8 = NEGF;
  if (lane == 0) {
    f0 = LB[2047];                                            // blank[0]
    f1 = bf2f_lo((uint32)*reinterpret_cast<const unsigned short*>(E + ((size_t)(b << 11) << 8)));
  }

  // ---- backward state init ----
  float h0, h1, h2, h3, h4, h5, h6, h7, h8;
  {
    const uint2 er = Erow[(size_t)((L - 1) << 6) + lane];
    const float e0 = bf2f_lo(er.x), e1 = bf2f_hi(er.x);
    const float e2 = bf2f_lo(er.y), e3 = bf2f_hi(er.y);
    const float blankL = LB[L - 2];                           // blank[L-1]
    const int s0 = 8 * lane, tb2 = 2 * tl, tm = 2 * tl - 1;
    h0 = (s0     == tb2) ? blankL : NEGF;
    h1 = (s0 + 1 == tm) ? e0     : NEGF;
    h2 = (s0 + 2 == tb2) ? blankL : NEGF;
    h3 = (s0 + 3 == tm) ? e1     : NEGF;
    h4 = (s0 + 4 == tb2) ? blankL : NEGF;
    h5 = (s0 + 5 == tm) ? e2     : NEGF;
    h6 = (s0 + 6 == tb2) ? blankL : NEGF;
    h7 = (s0 + 7 == tm) ? e3     : NEGF;
    h8 = ((lane == 63) && (tb2 == 512)) ? blankL : NEGF;
  }

  // ---- prefetch rings ----
  uint2  pf[PG][4];  float4 pb4[PG];      // fwd: emissions + blank float4
  uint2  qf[PG][4];  float  qb[PG][4];    // bwd: emissions + blank scalars
  auto fetchf = [&](int slot, int k) {
    const int kk = (k > 511) ? 511 : k;
#pragma unroll
    for (int j = 0; j < 4; ++j) {
      int r = 1 + 4 * kk + j; r = (r > 2047) ? 2047 : r;
      pf[slot][j] = Erow[(size_t)(r << 6) + lane];
    }
    pb4[slot] = reinterpret_cast<const float4*>(LB)[kk];      // blank[4kk+1..4kk+4]
  };
  auto fetchb = [&](int slot, int k) {
#pragma unroll
    for (int j = 0; j < 4; ++j) {
      int r = L - 2 - 4 * k - j; r = (r < 1) ? 1 : r;
      qf[slot][j] = Erow[(size_t)(r << 6) + lane];
      qb[slot][j] = LB[r - 1];                                // blank[r]
    }
  };
  auto stepf = [&](uint2 em, float eb) {
    const float e0 = bf2f_lo(em.x), e1 = bf2f_hi(em.x);
    const float e2 = bf2f_lo(em.y), e3 = bf2f_hi(em.y);
    const float am1 = dpp_shr1(NEGF, f7);                     // lane0 -> NEGF
    const float x0 = fmaxf(f0, am1) + eb;
    const float x1 = fmaxf(fmaxf(f1, f0), sk0 ? am1 : NEGF) + e0;
    const float x2 = fmaxf(f2, f1) + eb;
    const float x3 = fmaxf(fmaxf(f3, f2), sk1 ? f1 : NEGF) + e1;
    const float x4 = fmaxf(f4, f3) + eb;
    const float x5 = fmaxf(fmaxf(f5, f4), sk2 ? f3 : NEGF) + e2;
    const float x6 = fmaxf(f6, f5) + eb;
    const float x7 = fmaxf(fmaxf(f7, f6), sk3 ? f5 : NEGF) + e3;
    const float x8 = fmaxf(f8, f7) + eb;
    f0 = x0; f1 = x1; f2 = x2; f3 = x3; f4 = x4; f5 = x5; f6 = x6; f7 = x7; f8 = x8;
  };
  auto steph = [&](uint2 em, float eb) {
    const float e0 = bf2f_lo(em.x), e1 = bf2f_hi(em.x);
    const float e2 = bf2f_lo(em.y), e3 = bf2f_hi(em.y);
    const float bn0 = dpp_shl1(h8, h0);     // lane l: h0[l+1]; lane63: own h8
    const float bn1 = dpp_shl1(NEGF, h1);   // lane l: h1[l+1]; lane63: NEGF
    const float y0 = fmaxf(h0, h1) + eb;
    const float y1 = fmaxf(fmaxf(h1, h2), kb0 ? h3 : NEGF) + e0;
    const float y2 = fmaxf(h2, h3) + eb;
    const float y3 = fmaxf(fmaxf(h3, h4), kb1 ? h5 : NEGF) + e1;
    const float y4 = fmaxf(h4, h5) + eb;
    const float y5 = fmaxf(fmaxf(h5, h6), kb2 ? h7 : NEGF) + e2;
    const float y6 = fmaxf(h6, h7) + eb;
    const float y7 = fmaxf(fmaxf(h7, bn0), kb3 ? bn1 : NEGF) + e3;
    const float y8 = h8 + eb;
    h0 = y0; h1 = y1; h2 = y2; h3 = y3; h4 = y4; h5 = y5; h6 = y6; h7 = y7; h8 = y8;
  };

  const int nf = M, nb = L - 2 - M;          // nb == nf or nf+1
  const int Gf = nf >> 2, remf = nf & 3;
  const int Gb = nb >> 2, remb = nb & 3;
  const int Gmin = (Gf < Gb) ? Gf : Gb;      // |Gf-Gb| <= 1

#pragma unroll
  for (int s = 0; s < PG; ++s) { fetchf(s, s); fetchb(s, s); }
  __builtin_amdgcn_sched_barrier(0);

  // ---- interleaved main loop: both chains in one basic block ----
  int g = 0;
  while (g + PG <= Gmin) {
#pragma unroll
    for (int s = 0; s < PG; ++s) {
#pragma unroll
      for (int j = 0; j < 4; ++j) {
        stepf(pf[s][j], (&pb4[s].x)[j]);
        steph(qf[s][j], qb[s][j]);
      }
      fetchf(s, g + s + PG);
      fetchb(s, g + s + PG);
      __builtin_amdgcn_sched_barrier(0);
    }
    g += PG;
  }

  // ---- fwd tail (slots 0..PG-1 hold groups g..g+PG-1) ----
  {
    const int leftf = Gf - g;                // 0..PG (PG only if Gf == Gmin+1)
#pragma unroll
    for (int s = 0; s < PG; ++s) {
      if (s < leftf) {
#pragma unroll
        for (int j = 0; j < 4; ++j) stepf(pf[s][j], (&pb4[s].x)[j]);
      }
    }
    if (leftf == PG) {
      if (remf) {
        fetchf(0, g + PG);                   // one fresh, latency-exposed fetch
#pragma unroll
        for (int j = 0; j < 4; ++j)
          if (j < remf) stepf(pf[0][j], (&pb4[0].x)[j]);
      }
    } else {
#pragma unroll
      for (int s = 0; s < PG; ++s) {
        if (s == leftf) {
#pragma unroll
          for (int j = 0; j < 4; ++j)
            if (j < remf) stepf(pf[s][j], (&pb4[s].x)[j]);
        }
      }
    }
  }

  // ---- bwd tail ----
  {
    const int leftb = Gb - g;                // 0..PG (PG only if Gb == Gmin+1)
#pragma unroll
    for (int s = 0; s < PG; ++s) {
      if (s < leftb) {
#pragma unroll
        for (int j = 0; j < 4; ++j) steph(qf[s][j], qb[s][j]);
      }
    }
    if (leftb == PG) {
      if (remb) {
        fetchb(0, g + PG);
#pragma unroll
        for (int j = 0; j < 4; ++j)
          if (j < remb) steph(qf[0][j], qb[0][j]);
      }
    } else {
#pragma unroll
      for (int s = 0; s < PG; ++s) {
        if (s == leftb) {
#pragma unroll
          for (int j = 0; j < 4; ++j)
            if (j < remb) steph(qf[s][j], qb[s][j]);
        }
      }
    }
  }

  // ---- dump beta[M+1] to LDS (+NEG padding), wave-internal handoff ----
  Bt[8 * lane + 0] = h0; Bt[8 * lane + 1] = h1;
  Bt[8 * lane + 2] = h2; Bt[8 * lane + 3] = h3;
  Bt[8 * lane + 4] = h4; Bt[8 * lane + 5] = h5;
  Bt[8 * lane + 6] = h6; Bt[8 * lane + 7] = h7;
  if (lane == 63) Bt[512] = h8;
  if (lane == 0) { Bt[513] = NEGF; Bt[514] = NEGF; }
  __syncthreads();

  // ---- merge (identical math to baseline) ----
  {
    const int s0 = 8 * lane;
    float best;
    best =             f0 + fmaxf(Bt[s0],     Bt[s0 + 1]);
    best = fmaxf(best, f1 + fmaxf(fmaxf(Bt[s0 + 1], Bt[s0 + 2]), kb0 ? Bt[s0 + 3] : NEGF));
    best = fmaxf(best, f2 + fmaxf(Bt[s0 + 2], Bt[s0 + 3]));
    best = fmaxf(best, f3 + fmaxf(fmaxf(Bt[s0 + 3], Bt[s0 + 4]), kb1 ? Bt[s0 + 5] : NEGF));
    best = fmaxf(best, f4 + fmaxf(Bt[s0 + 4], Bt[s0 + 5]));
    best = fmaxf(best, f5 + fmaxf(fmaxf(Bt[s0 + 5], Bt[s0 + 6]), kb2 ? Bt[s0 + 7] : NEGF));
    best = fmaxf(best, f6 + fmaxf(Bt[s0 + 6], Bt[s0 + 7]));
    best = fmaxf(best, f7 + fmaxf(fmaxf(Bt[s0 + 7], Bt[s0 + 8]), kb3 ? Bt[s0 + 9] : NEGF));
    best = fmaxf(best, f8 + Bt[512]);
#pragma unroll
    for (int off = 32; off; off >>= 1) best = fmaxf(best, __shfl_down(best, off));
    if (lane == 0) atomicAdd(acc, -best);
  }
}

// ---------------------------------------------------------------------------
// Kernel C: out = acc / sum(L_b)
// ---------------------------------------------------------------------------
__global__ __launch_bounds__(64) void finalize_kernel(
    const int* __restrict__ llen, const float* __restrict__ acc,
    float* __restrict__ out) {
  int Lsum = llen[threadIdx.x];   // B == 64 == blockDim
#pragma unroll
  for (int off = 32; off; off >>= 1) Lsum += __shfl_down(Lsum, off);
  if (threadIdx.x == 0) out[0] = acc[0] / (float)Lsum;
}

extern "C" void kernel_launch(void* const* d_in, const int* in_sizes, int n_in,
                              void* d_out, int out_size, void* d_ws, size_t ws_size,
                              hipStream_t stream) {
  const float* logits  = (const float*)d_in[0];   // [B,T,V] fp32
  const int*   targets = (const int*)d_in[1];     // [B,U] int32
  const int*   llen    = (const int*)d_in[2];     // [B]
  const int*   tlen    = (const int*)d_in[3];     // [B]
  float* out = (float*)d_out;

  // ws layout: [0,16) acc | [4096, 4096+512K) Ebs fp32 | [1MiB, 1MiB+64MiB) E bf16
  float*          acc = (float*)d_ws;
  float*          Ebs = (float*)((char*)d_ws + 4096);
  unsigned short* E   = (unsigned short*)((char*)d_ws + (1u << 20));

  hipMemsetAsync(acc, 0, 16, stream);
  gather_lse_kernel<<<Bb * 32, 256, 0, stream>>>(logits, targets, llen, acc, Ebs, E);
  viterbi_kernel<<<Bb, 64, 0, stream>>>(E, Ebs, targets, llen, tlen, acc);
  finalize_kernel<<<1, 64, 0, stream>>>(llen, acc, out);
}

// Round 2
// 288.210 us; speedup vs baseline: 1.1803x; 1.1803x over previous
//
#include <hip/hip_runtime.h>

#define NEGF -1e30f
typedef unsigned int uint32;

static constexpr int Bb = 64, Tt = 2048, Vv = 256, Uu = 256;
// S = 2*U+1 = 513 states.
// R9: state-split Viterbi. 4 waves per batch:
//   wv0 fwd-lo  (states 0..255,   producer of alpha[255] boundary)
//   wv1 fwd-hi  (states 256..512, consumer, lags one K-chunk)
//   wv2 bwd-hi  (states 256..512, producer of beta[256],beta[257])
//   wv3 bwd-lo  (states 0..255,   consumer, lags one K-chunk)
// Rationale: single-wave issue cadence ~5 cyc/instr (R7: 31 slots -> 190 cyc;
// R8: 70 slots -> 333 cyc). Serial DP speed == instr/step, so halve it per wave.

__device__ __forceinline__ unsigned short f2bf(float f) {    // RNE, no NaN inputs
  uint32 u = __builtin_bit_cast(uint32, f);
  u += 0x7fffu + ((u >> 16) & 1u);
  return (unsigned short)(u >> 16);
}
__device__ __forceinline__ float bf2f_lo(uint32 p) { return __builtin_bit_cast(float, p << 16); }
__device__ __forceinline__ float bf2f_hi(uint32 p) { return __builtin_bit_cast(float, p & 0xffff0000u); }

// DPP wave shifts: shr1: lane l <- l-1 (lane0 keeps old); shl1: lane l <- l+1 (lane63 keeps old).
__device__ __forceinline__ float dpp_shr1(float old, float src) {
  return __builtin_bit_cast(float, __builtin_amdgcn_update_dpp(
      __builtin_bit_cast(int, old), __builtin_bit_cast(int, src), 0x138, 0xF, 0xF, false));
}
__device__ __forceinline__ float dpp_shl1(float old, float src) {
  return __builtin_bit_cast(float, __builtin_amdgcn_update_dpp(
      __builtin_bit_cast(int, old), __builtin_bit_cast(int, src), 0x130, 0xF, 0xF, false));
}

// ---------------------------------------------------------------------------
// Kernel A (unchanged): streaming pass over logits.
// ---------------------------------------------------------------------------
__global__ __launch_bounds__(256) void gather_lse_kernel(
    const float* __restrict__ logits, const int* __restrict__ targets,
    const int* __restrict__ llen, float* __restrict__ acc,
    float* __restrict__ Ebs, unsigned short* __restrict__ E) {
  __shared__ __align__(16) float buf[4][8][Vv];   // 32 KB
  __shared__ float wpart[4];
  const int b = blockIdx.x >> 5;
  const int c = blockIdx.x & 31;
  const int w = threadIdx.x >> 6;
  const int lane = threadIdx.x & 63;
  const int L = llen[b];
  const int4 lb = reinterpret_cast<const int4*>(targets + (b << 8))[lane];
  const float* __restrict__ lgb = logits + (size_t)b * (Tt * Vv);
  float lse_local = 0.f;
#pragma unroll
  for (int k = 0; k < 2; ++k) {
    const int tbase = (c << 6) + (k << 5) + w;
    if (tbase >= L) break;                        // wave-uniform
    float4 v[8];
#pragma unroll
    for (int j = 0; j < 8; ++j)
      v[j] = reinterpret_cast<const float4*>(lgb + (size_t)(tbase + 4 * j) * Vv)[lane];
    float s[8];
#pragma unroll
    for (int j = 0; j < 8; ++j)
      s[j] = __expf(v[j].x) + __expf(v[j].y) + __expf(v[j].z) + __expf(v[j].w);
#pragma unroll
    for (int off = 32; off; off >>= 1) {
#pragma unroll
      for (int j = 0; j < 8; ++j) s[j] += __shfl_down(s[j], off);
    }
#pragma unroll
    for (int j = 0; j < 8; ++j)
      reinterpret_cast<float4*>(&buf[w][j][0])[lane] = v[j];
#pragma unroll
    for (int j = 0; j < 8; ++j) {
      const int t = tbase + 4 * j;
      const bool val = t < L;
      ushort4 o;
      o.x = f2bf(buf[w][j][lb.x]); o.y = f2bf(buf[w][j][lb.y]);
      o.z = f2bf(buf[w][j][lb.z]); o.w = f2bf(buf[w][j][lb.w]);
      if (val)
        reinterpret_cast<ushort4*>(E + ((size_t)((b << 11) + t)) * Vv)[lane] = o;
      if ((lane == 0) & val) {
        lse_local += __logf(s[j]);
        Ebs[(b << 11) + ((t == 0) ? 2047 : t - 1)] = v[j].x;
      }
    }
  }
  if (lane == 0) wpart[w] = lse_local;
  __syncthreads();
  if (threadIdx.x == 0)
    atomicAdd(acc, wpart[0] + wpart[1] + wpart[2] + wpart[3]);
}

// ---------------------------------------------------------------------------
// Kernel B: state-split bidirectional Viterbi.
// ---------------------------------------------------------------------------
#define PG   4      // ring depth (groups of 4 steps)
#define KCH  64     // steps per chunk/phase
#define GPP  16     // groups per phase (KCH/4)
#define REVS 4      // ring revolutions per phase (GPP/PG)

__global__ __launch_bounds__(256, 1) void viterbi_kernel(
    const unsigned short* __restrict__ E, const float* __restrict__ Ebs,
    const int* __restrict__ targets, const int* __restrict__ llen,
    const int* __restrict__ tlen, float* __restrict__ acc) {
  __shared__ __align__(16) float LB[2048];        // shifted blanks, 8 KB
  __shared__ __align__(16) float Bf[2][KCH];      // alpha[255] pre-step snapshots
  __shared__ __align__(16) float Bb0[2][KCH];     // beta[256] pre-step
  __shared__ __align__(16) float Bb1[2][KCH];     // beta[257] pre-step
  __shared__ __align__(16) float Bt[520];
  __shared__ float Pm[2];
  const int b = blockIdx.x;
  const int lane = threadIdx.x & 63;
  const int wv = threadIdx.x >> 6;
  const int L = llen[b];
  const int tl = tlen[b];
  const int M = (L - 2) >> 1;
  const int nbl = L - 2 - M;                      // nbl >= M
  const int P = (nbl + KCH - 1) / KCH + 1;        // phases (consumer lags 1 chunk)
  const int hiw = (wv == 1 || wv == 2) ? 64 : 0;  // hi waves read words 64..127
  const uint32* __restrict__ Er =
      reinterpret_cast<const uint32*>(E) + ((size_t)b << 11) * 128 + hiw + lane;
  const float* __restrict__ Ebb = Ebs + (b << 11);

  {  // cooperative blank preload (2048 floats, 4 waves)
    const float4* src = reinterpret_cast<const float4*>(Ebb);
    float4* dst = reinterpret_cast<float4*>(LB);
    for (int i = threadIdx.x; i < 512; i += 256) dst[i] = src[i];
  }
  __syncthreads();

  if (wv == 0) {
    // ================= fwd-lo (producer) : states 4l..4l+3 =================
    const int2 tt = reinterpret_cast<const int2*>(targets + (b << 8))[lane];
    const int prev = __shfl_up(tt.y, 1);
    const bool sk0 = (lane != 0) && (tt.x != prev);
    const bool sk1 = (tt.y != tt.x);
    float a0 = NEGF, a1 = NEGF, a2 = NEGF, a3 = NEGF;
    if (lane == 0) { a0 = LB[2047]; a1 = bf2f_lo(Er[0]); }
    uint32 pf[PG][4]; float4 pb[PG];
    auto fetch = [&](int slot, int g) {
#pragma unroll
      for (int j = 0; j < 4; ++j) {
        int r = 1 + 4 * g + j; r = (r > 2047) ? 2047 : r;
        pf[slot][j] = Er[(size_t)r * 128];
      }
      int kk = (g > 511) ? 511 : g;
      pb[slot] = reinterpret_cast<const float4*>(LB)[kk];
    };
    auto step = [&](uint32 em, float eb) {
      const float e0 = bf2f_lo(em), e1 = bf2f_hi(em);
      const float am1 = dpp_shr1(NEGF, a3);
      const float x0 = fmaxf(a0, am1) + eb;
      const float x1 = fmaxf(fmaxf(a1, a0), sk0 ? am1 : NEGF) + e0;
      const float x2 = fmaxf(a2, a1) + eb;
      const float x3 = fmaxf(fmaxf(a3, a2), sk1 ? a1 : NEGF) + e1;
      a0 = x0; a1 = x1; a2 = x2; a3 = x3;
    };
    const int n = M;
#pragma unroll
    for (int s = 0; s < PG; ++s) fetch(s, s);
    __builtin_amdgcn_sched_barrier(0);
    for (int p = 0; p < P; ++p) {
      float* Bw = Bf[p & 1];
      const int gbase = p * GPP;
      for (int rev = 0; rev < REVS; ++rev) {
#pragma unroll
        for (int s = 0; s < PG; ++s) {
          const int q = rev * PG + s;
          const int g = gbase + q;
          const int st0 = 4 * g;
          if (st0 < n) {
            float s0 = a3, s1, s2, s3;
            if (st0 + 4 <= n) {
              step(pf[s][0], pb[s].x); s1 = a3;
              step(pf[s][1], pb[s].y); s2 = a3;
              step(pf[s][2], pb[s].z); s3 = a3;
              step(pf[s][3], pb[s].w);
            } else {
              const int rem = n - st0;
              step(pf[s][0], pb[s].x); s1 = a3;
              if (rem > 1) step(pf[s][1], pb[s].y); s2 = a3;
              if (rem > 2) step(pf[s][2], pb[s].z); s3 = a3;
            }
            if (lane == 63) *reinterpret_cast<float4*>(&Bw[4 * q]) = make_float4(s0, s1, s2, s3);
          }
          fetch(s, g + PG);
          __builtin_amdgcn_sched_barrier(0);
        }
      }
      asm volatile("s_waitcnt lgkmcnt(0)" ::: "memory");
      __builtin_amdgcn_sched_barrier(0);
      __builtin_amdgcn_s_barrier();
    }
    // dump barrier (bwd waves publish Bt)
    asm volatile("s_waitcnt lgkmcnt(0)" ::: "memory");
    __builtin_amdgcn_sched_barrier(0);
    __builtin_amdgcn_s_barrier();
    // merge over states 4l..4l+3
    const int t128 = targets[(b << 8) + 128];
    const int nx = __shfl_down(tt.x, 1);
    const bool m1 = (lane == 63) ? (t128 != tt.y) : (nx != tt.y);
    const int s0 = 4 * lane;
    float best;
    best =             a0 + fmaxf(Bt[s0],     Bt[s0 + 1]);
    best = fmaxf(best, a1 + fmaxf(fmaxf(Bt[s0 + 1], Bt[s0 + 2]), sk1 ? Bt[s0 + 3] : NEGF));
    best = fmaxf(best, a2 + fmaxf(Bt[s0 + 2], Bt[s0 + 3]));
    best = fmaxf(best, a3 + fmaxf(fmaxf(Bt[s0 + 3], Bt[s0 + 4]), m1 ? Bt[s0 + 5] : NEGF));
#pragma unroll
    for (int off = 32; off; off >>= 1) best = fmaxf(best, __shfl_down(best, off));
    if (lane == 0) Pm[0] = best;

  } else if (wv == 1) {
    // ================= fwd-hi (consumer) : states 256+4l..+3, +512 =========
    const int2 tt = reinterpret_cast<const int2*>(targets + (b << 8))[64 + lane];
    const int t127 = targets[(b << 8) + 127];
    const int pw = __shfl_up(tt.y, 1);
    const int prevh = (lane == 0) ? t127 : pw;
    const bool skh0 = (tt.x != prevh);            // s-2 = state 255+4l always exists
    const bool skh1 = (tt.y != tt.x);
    float a0 = NEGF, a1 = NEGF, a2 = NEGF, a3 = NEGF, a4 = NEGF;
    uint32 pf[PG][4]; float4 pb[PG];
    auto fetch = [&](int slot, int g) {
#pragma unroll
      for (int j = 0; j < 4; ++j) {
        int r = 1 + 4 * g + j; r = (r > 2047) ? 2047 : r;
        pf[slot][j] = Er[(size_t)r * 128];
      }
      int kk = (g > 511) ? 511 : g;
      pb[slot] = reinterpret_cast<const float4*>(LB)[kk];
    };
    auto step = [&](uint32 em, float eb, float bv) {
      const float e0 = bf2f_lo(em), e1 = bf2f_hi(em);
      const float am1 = dpp_shr1(bv, a3);         // lane0 <- boundary alpha[255]
      const float x0 = fmaxf(a0, am1) + eb;
      const float x1 = fmaxf(fmaxf(a1, a0), skh0 ? am1 : NEGF) + e0;
      const float x2 = fmaxf(a2, a1) + eb;
      const float x3 = fmaxf(fmaxf(a3, a2), skh1 ? a1 : NEGF) + e1;
      const float x4 = fmaxf(a4, a3) + eb;        // state 512 (lane63 only meaningful)
      a0 = x0; a1 = x1; a2 = x2; a3 = x3; a4 = x4;
    };
    const int n = M;
#pragma unroll
    for (int s = 0; s < PG; ++s) fetch(s, s);
    __builtin_amdgcn_sched_barrier(0);
    for (int p = 0; p < P; ++p) {
      if (p >= 1) {
        const float* Bw = Bf[(p - 1) & 1];
        const int gbase = (p - 1) * GPP;
        float4 bvA = reinterpret_cast<const float4*>(Bw)[0], bvB;
        for (int rev = 0; rev < REVS; ++rev) {
#pragma unroll
          for (int s = 0; s < PG; ++s) {
            const int q = rev * PG + s;
            const int g = gbase + q;
            const int st0 = 4 * g;
            const int qn = (q < GPP - 1) ? (q + 1) : (GPP - 1);
            float4 bv;
            if (!(s & 1)) { bvB = reinterpret_cast<const float4*>(Bw)[qn]; bv = bvA; }
            else          { bvA = reinterpret_cast<const float4*>(Bw)[qn]; bv = bvB; }
            if (st0 < n) {
              if (st0 + 4 <= n) {
                step(pf[s][0], pb[s].x, bv.x);
                step(pf[s][1], pb[s].y, bv.y);
                step(pf[s][2], pb[s].z, bv.z);
                step(pf[s][3], pb[s].w, bv.w);
              } else {
                const int rem = n - st0;
                step(pf[s][0], pb[s].x, bv.x);
                if (rem > 1) step(pf[s][1], pb[s].y, bv.y);
                if (rem > 2) step(pf[s][2], pb[s].z, bv.z);
              }
            }
            fetch(s, g + PG);
            __builtin_amdgcn_sched_barrier(0);
          }
        }
      }
      asm volatile("s_waitcnt lgkmcnt(0)" ::: "memory");
      __builtin_amdgcn_sched_barrier(0);
      __builtin_amdgcn_s_barrier();
    }
    asm volatile("s_waitcnt lgkmcnt(0)" ::: "memory");
    __builtin_amdgcn_sched_barrier(0);
    __builtin_amdgcn_s_barrier();
    // merge over states 256+4l..+3 (+512)
    const int nxh = __shfl_down(tt.x, 1);
    const bool m1 = (lane < 63) && (nxh != tt.y);
    const int s0 = 256 + 4 * lane;
    float best;
    best =             a0 + fmaxf(Bt[s0],     Bt[s0 + 1]);
    best = fmaxf(best, a1 + fmaxf(fmaxf(Bt[s0 + 1], Bt[s0 + 2]), skh1 ? Bt[s0 + 3] : NEGF));
    best = fmaxf(best, a2 + fmaxf(Bt[s0 + 2], Bt[s0 + 3]));
    best = fmaxf(best, a3 + fmaxf(fmaxf(Bt[s0 + 3], Bt[s0 + 4]), m1 ? Bt[s0 + 5] : NEGF));
    best = fmaxf(best, (lane == 63) ? (a4 + Bt[512]) : NEGF);
#pragma unroll
    for (int off = 32; off; off >>= 1) best = fmaxf(best, __shfl_down(best, off));
    if (lane == 0) Pm[1] = best;

  } else if (wv == 2) {
    // ================= bwd-hi (producer) : states 256+4l..+3, +512 =========
    const int2 tt = reinterpret_cast<const int2*>(targets + (b << 8))[64 + lane];
    const int nxh = __shfl_down(tt.x, 1);
    const bool kb0 = (tt.y != tt.x);
    const bool kb1 = (lane < 63) && (nxh != tt.y);
    float h0, h1, h2, h3, h4;
    {
      const uint32 er = Er[(size_t)(L - 1) * 128];
      const float e0 = bf2f_lo(er), e1 = bf2f_hi(er);
      const float blankL = LB[L - 2];
      const int s0h = 256 + 4 * lane, tb2 = 2 * tl, tm = 2 * tl - 1;
      h0 = (s0h     == tb2) ? blankL : NEGF;
      h1 = (s0h + 1 == tm ) ? e0     : NEGF;
      h2 = (s0h + 2 == tb2) ? blankL : NEGF;
      h3 = (s0h + 3 == tm ) ? e1     : NEGF;
      h4 = ((lane == 63) && (tb2 == 512)) ? blankL : NEGF;
    }
    uint32 qf[PG][4]; float qb[PG][4];
    auto fetch = [&](int slot, int g) {
#pragma unroll
      for (int j = 0; j < 4; ++j) {
        int r = L - 2 - 4 * g - j; r = (r < 1) ? 1 : r;
        qf[slot][j] = Er[(size_t)r * 128];
        qb[slot][j] = LB[r - 1];
      }
    };
    auto step = [&](uint32 em, float eb) {
      const float e0 = bf2f_lo(em), e1 = bf2f_hi(em);
      const float bn0 = dpp_shl1(h4, h0);
      const float bn1 = dpp_shl1(NEGF, h1);
      const float y0 = fmaxf(h0, h1) + eb;
      const float y1 = fmaxf(fmaxf(h1, h2), kb0 ? h3 : NEGF) + e0;
      const float y2 = fmaxf(h2, h3) + eb;
      const float y3 = fmaxf(fmaxf(h3, bn0), kb1 ? bn1 : NEGF) + e1;
      const float y4 = h4 + eb;
      h0 = y0; h1 = y1; h2 = y2; h3 = y3; h4 = y4;
    };
    const int n = nbl;
#pragma unroll
    for (int s = 0; s < PG; ++s) fetch(s, s);
    __builtin_amdgcn_sched_barrier(0);
    for (int p = 0; p < P; ++p) {
      float* Bw0 = Bb0[p & 1];
      float* Bw1 = Bb1[p & 1];
      const int gbase = p * GPP;
      for (int rev = 0; rev < REVS; ++rev) {
#pragma unroll
        for (int s = 0; s < PG; ++s) {
          const int q = rev * PG + s;
          const int g = gbase + q;
          const int st0 = 4 * g;
          if (st0 < n) {
            float u0 = h0, v0 = h1, u1, v1, u2, v2, u3, v3;
            if (st0 + 4 <= n) {
              step(qf[s][0], qb[s][0]); u1 = h0; v1 = h1;
              step(qf[s][1], qb[s][1]); u2 = h0; v2 = h1;
              step(qf[s][2], qb[s][2]); u3 = h0; v3 = h1;
              step(qf[s][3], qb[s][3]);
            } else {
              const int rem = n - st0;
              step(qf[s][0], qb[s][0]); u1 = h0; v1 = h1;
              if (rem > 1) step(qf[s][1], qb[s][1]); u2 = h0; v2 = h1;
              if (rem > 2) step(qf[s][2], qb[s][2]); u3 = h0; v3 = h1;
            }
            if (lane == 0) {
              *reinterpret_cast<float4*>(&Bw0[4 * q]) = make_float4(u0, u1, u2, u3);
              *reinterpret_cast<float4*>(&Bw1[4 * q]) = make_float4(v0, v1, v2, v3);
            }
          }
          fetch(s, g + PG);
          __builtin_amdgcn_sched_barrier(0);
        }
      }
      asm volatile("s_waitcnt lgkmcnt(0)" ::: "memory");
      __builtin_amdgcn_sched_barrier(0);
      __builtin_amdgcn_s_barrier();
    }
    Bt[256 + 4 * lane + 0] = h0; Bt[256 + 4 * lane + 1] = h1;
    Bt[256 + 4 * lane + 2] = h2; Bt[256 + 4 * lane + 3] = h3;
    if (lane == 63) Bt[512] = h4;
    if (lane == 0) { Bt[513] = NEGF; Bt[514] = NEGF; }
    asm volatile("s_waitcnt lgkmcnt(0)" ::: "memory");
    __builtin_amdgcn_sched_barrier(0);
    __builtin_amdgcn_s_barrier();

  } else {
    // ================= bwd-lo (consumer) : states 4l..4l+3 =================
    const int2 tt = reinterpret_cast<const int2*>(targets + (b << 8))[lane];
    const int t128 = targets[(b << 8) + 128];
    const int nx = __shfl_down(tt.x, 1);
    const bool kb0 = (tt.y != tt.x);
    const bool kb1 = (lane == 63) ? (t128 != tt.y) : (nx != tt.y);
    float h0, h1, h2, h3;
    {
      const uint32 er = Er[(size_t)(L - 1) * 128];
      const float e0 = bf2f_lo(er), e1 = bf2f_hi(er);
      const float blankL = LB[L - 2];
      const int s0 = 4 * lane, tb2 = 2 * tl, tm = 2 * tl - 1;
      h0 = (s0     == tb2) ? blankL : NEGF;
      h1 = (s0 + 1 == tm ) ? e0     : NEGF;
      h2 = (s0 + 2 == tb2) ? blankL : NEGF;
      h3 = (s0 + 3 == tm ) ? e1     : NEGF;
    }
    uint32 qf[PG][4]; float qb[PG][4];
    auto fetch = [&](int slot, int g) {
#pragma unroll
      for (int j = 0; j < 4; ++j) {
        int r = L - 2 - 4 * g - j; r = (r < 1) ? 1 : r;
        qf[slot][j] = Er[(size_t)r * 128];
        qb[slot][j] = LB[r - 1];
      }
    };
    auto step = [&](uint32 em, float eb, float bv0, float bv1) {
      const float e0 = bf2f_lo(em), e1 = bf2f_hi(em);
      const float bn0 = dpp_shl1(bv0, h0);        // lane63 <- beta[256]
      const float bn1 = dpp_shl1(bv1, h1);        // lane63 <- beta[257]
      const float y0 = fmaxf(h0, h1) + eb;
      const float y1 = fmaxf(fmaxf(h1, h2), kb0 ? h3 : NEGF) + e0;
      const float y2 = fmaxf(h2, h3) + eb;
      const float y3 = fmaxf(fmaxf(h3, bn0), kb1 ? bn1 : NEGF) + e1;
      h0 = y0; h1 = y1; h2 = y2; h3 = y3;
    };
    const int n = nbl;
#pragma unroll
    for (int s = 0; s < PG; ++s) fetch(s, s);
    __builtin_amdgcn_sched_barrier(0);
    for (int p = 0; p < P; ++p) {
      if (p >= 1) {
        const float* Bw0 = Bb0[(p - 1) & 1];
        const float* Bw1 = Bb1[(p - 1) & 1];
        const int gbase = (p - 1) * GPP;
        float4 b0A = reinterpret_cast<const float4*>(Bw0)[0], b0B;
        float4 b1A = reinterpret_cast<const float4*>(Bw1)[0], b1B;
        for (int rev = 0; rev < REVS; ++rev) {
#pragma unroll
          for (int s = 0; s < PG; ++s) {
            const int q = rev * PG + s;
            const int g = gbase + q;
            const int st0 = 4 * g;
            const int qn = (q < GPP - 1) ? (q + 1) : (GPP - 1);
            float4 c0, c1;
            if (!(s & 1)) {
              b0B = reinterpret_cast<const float4*>(Bw0)[qn];
              b1B = reinterpret_cast<const float4*>(Bw1)[qn];
              c0 = b0A; c1 = b1A;
            } else {
              b0A = reinterpret_cast<const float4*>(Bw0)[qn];
              b1A = reinterpret_cast<const float4*>(Bw1)[qn];
              c0 = b0B; c1 = b1B;
            }
            if (st0 < n) {
              if (st0 + 4 <= n) {
                step(qf[s][0], qb[s][0], c0.x, c1.x);
                step(qf[s][1], qb[s][1], c0.y, c1.y);
                step(qf[s][2], qb[s][2], c0.z, c1.z);
                step(qf[s][3], qb[s][3], c0.w, c1.w);
              } else {
                const int rem = n - st0;
                step(qf[s][0], qb[s][0], c0.x, c1.x);
                if (rem > 1) step(qf[s][1], qb[s][1], c0.y, c1.y);
                if (rem > 2) step(qf[s][2], qb[s][2], c0.z, c1.z);
              }
            }
            fetch(s, g + PG);
            __builtin_amdgcn_sched_barrier(0);
          }
        }
      }
      asm volatile("s_waitcnt lgkmcnt(0)" ::: "memory");
      __builtin_amdgcn_sched_barrier(0);
      __builtin_amdgcn_s_barrier();
    }
    Bt[4 * lane + 0] = h0; Bt[4 * lane + 1] = h1;
    Bt[4 * lane + 2] = h2; Bt[4 * lane + 3] = h3;
    asm volatile("s_waitcnt lgkmcnt(0)" ::: "memory");
    __builtin_amdgcn_sched_barrier(0);
    __builtin_amdgcn_s_barrier();
  }

  __syncthreads();
  if (threadIdx.x == 0) atomicAdd(acc, -fmaxf(Pm[0], Pm[1]));
}

// ---------------------------------------------------------------------------
// Kernel C: out = acc / sum(L_b)
// ---------------------------------------------------------------------------
__global__ __launch_bounds__(64) void finalize_kernel(
    const int* __restrict__ llen, const float* __restrict__ acc,
    float* __restrict__ out) {
  int Lsum = llen[threadIdx.x];
#pragma unroll
  for (int off = 32; off; off >>= 1) Lsum += __shfl_down(Lsum, off);
  if (threadIdx.x == 0) out[0] = acc[0] / (float)Lsum;
}

extern "C" void kernel_launch(void* const* d_in, const int* in_sizes, int n_in,
                              void* d_out, int out_size, void* d_ws, size_t ws_size,
                              hipStream_t stream) {
  const float* logits  = (const float*)d_in[0];   // [B,T,V] fp32
  const int*   targets = (const int*)d_in[1];     // [B,U] int32
  const int*   llen    = (const int*)d_in[2];     // [B]
  const int*   tlen    = (const int*)d_in[3];     // [B]
  float* out = (float*)d_out;

  // ws layout: [0,16) acc | [4096, 4096+512K) Ebs fp32 | [1MiB, 1MiB+64MiB) E bf16
  float*          acc = (float*)d_ws;
  float*          Ebs = (float*)((char*)d_ws + 4096);
  unsigned short* E   = (unsigned short*)((char*)d_ws + (1u << 20));

  hipMemsetAsync(acc, 0, 16, stream);
  gather_lse_kernel<<<Bb * 32, 256, 0, stream>>>(logits, targets, llen, acc, Ebs, E);
  viterbi_kernel<<<Bb, 256, 0, stream>>>(E, Ebs, targets, llen, tlen, acc);
  finalize_kernel<<<1, 64, 0, stream>>>(llen, acc, out);
}

// Round 3
// 287.494 us; speedup vs baseline: 1.1832x; 1.0025x over previous
//
#include <hip/hip_runtime.h>

#define NEGF -1e30f
typedef unsigned int uint32;

static constexpr int Bb = 64, Tt = 2048, Vv = 256, Uu = 256;
// S = 2*U+1 = 513 states.
// R10: state-split Viterbi (4 waves/batch: fwd-lo, fwd-hi, bwd-hi, bwd-lo)
// with I$-footprint shrink (rev loop NOT unrolled), PG=8 (32-step lookahead),
// KCH=128 (9 barriers), and no memset (plain-store partials).
// R9 post-mortem: 16-group unrolled phase body x 4 divergent wave variants
// ~= 30-40KB code > 32KB L1I -> ~10 cyc/slot cadence (R7: 5.4, R8: 4.8 with
// tiny bodies). Shrink code, keep slots/step halved.

__device__ __forceinline__ unsigned short f2bf(float f) {    // RNE, no NaN inputs
  uint32 u = __builtin_bit_cast(uint32, f);
  u += 0x7fffu + ((u >> 16) & 1u);
  return (unsigned short)(u >> 16);
}
__device__ __forceinline__ float bf2f_lo(uint32 p) { return __builtin_bit_cast(float, p << 16); }
__device__ __forceinline__ float bf2f_hi(uint32 p) { return __builtin_bit_cast(float, p & 0xffff0000u); }

// DPP wave shifts: shr1: lane l <- l-1 (lane0 keeps old); shl1: lane l <- l+1 (lane63 keeps old).
__device__ __forceinline__ float dpp_shr1(float old, float src) {
  return __builtin_bit_cast(float, __builtin_amdgcn_update_dpp(
      __builtin_bit_cast(int, old), __builtin_bit_cast(int, src), 0x138, 0xF, 0xF, false));
}
__device__ __forceinline__ float dpp_shl1(float old, float src) {
  return __builtin_bit_cast(float, __builtin_amdgcn_update_dpp(
      __builtin_bit_cast(int, old), __builtin_bit_cast(int, src), 0x130, 0xF, 0xF, false));
}

// ---------------------------------------------------------------------------
// Kernel A: streaming pass over logits (R10: plain-store partial, no atomic).
// ---------------------------------------------------------------------------
__global__ __launch_bounds__(256) void gather_lse_kernel(
    const float* __restrict__ logits, const int* __restrict__ targets,
    const int* __restrict__ llen, float* __restrict__ gpart,
    float* __restrict__ Ebs, unsigned short* __restrict__ E) {
  __shared__ __align__(16) float buf[4][8][Vv];   // 32 KB
  __shared__ float wpart[4];
  const int b = blockIdx.x >> 5;
  const int c = blockIdx.x & 31;
  const int w = threadIdx.x >> 6;
  const int lane = threadIdx.x & 63;
  const int L = llen[b];
  const int4 lb = reinterpret_cast<const int4*>(targets + (b << 8))[lane];
  const float* __restrict__ lgb = logits + (size_t)b * (Tt * Vv);
  float lse_local = 0.f;
#pragma unroll
  for (int k = 0; k < 2; ++k) {
    const int tbase = (c << 6) + (k << 5) + w;
    if (tbase >= L) break;                        // wave-uniform
    float4 v[8];
#pragma unroll
    for (int j = 0; j < 8; ++j)
      v[j] = reinterpret_cast<const float4*>(lgb + (size_t)(tbase + 4 * j) * Vv)[lane];
    float s[8];
#pragma unroll
    for (int j = 0; j < 8; ++j)
      s[j] = __expf(v[j].x) + __expf(v[j].y) + __expf(v[j].z) + __expf(v[j].w);
#pragma unroll
    for (int off = 32; off; off >>= 1) {
#pragma unroll
      for (int j = 0; j < 8; ++j) s[j] += __shfl_down(s[j], off);
    }
#pragma unroll
    for (int j = 0; j < 8; ++j)
      reinterpret_cast<float4*>(&buf[w][j][0])[lane] = v[j];
#pragma unroll
    for (int j = 0; j < 8; ++j) {
      const int t = tbase + 4 * j;
      const bool val = t < L;
      ushort4 o;
      o.x = f2bf(buf[w][j][lb.x]); o.y = f2bf(buf[w][j][lb.y]);
      o.z = f2bf(buf[w][j][lb.z]); o.w = f2bf(buf[w][j][lb.w]);
      if (val)
        reinterpret_cast<ushort4*>(E + ((size_t)((b << 11) + t)) * Vv)[lane] = o;
      if ((lane == 0) & val) {
        lse_local += __logf(s[j]);
        Ebs[(b << 11) + ((t == 0) ? 2047 : t - 1)] = v[j].x;
      }
    }
  }
  if (lane == 0) wpart[w] = lse_local;
  __syncthreads();
  if (threadIdx.x == 0)
    gpart[blockIdx.x] = wpart[0] + wpart[1] + wpart[2] + wpart[3];
}

// ---------------------------------------------------------------------------
// Kernel B: state-split bidirectional Viterbi.
// ---------------------------------------------------------------------------
#define PG   8      // ring depth (groups of 4 steps) -> 32-step lookahead
#define KCH  128    // steps per chunk/phase
#define GPP  32     // groups per phase (KCH/4)
#define REVS 4      // ring revolutions per phase (GPP/PG)

__global__ __launch_bounds__(256, 1) void viterbi_kernel(
    const unsigned short* __restrict__ E, const float* __restrict__ Ebs,
    const int* __restrict__ targets, const int* __restrict__ llen,
    const int* __restrict__ tlen, float* __restrict__ vpart) {
  __shared__ __align__(16) float LB[2048];        // shifted blanks, 8 KB
  __shared__ __align__(16) float Bf[2][KCH];      // alpha[255] pre-step snapshots
  __shared__ __align__(16) float Bb0[2][KCH];     // beta[256] pre-step
  __shared__ __align__(16) float Bb1[2][KCH];     // beta[257] pre-step
  __shared__ __align__(16) float Bt[520];
  __shared__ float Pm[2];
  const int b = blockIdx.x;
  const int lane = threadIdx.x & 63;
  const int wv = threadIdx.x >> 6;
  const int L = llen[b];
  const int tl = tlen[b];
  const int M = (L - 2) >> 1;
  const int nbl = L - 2 - M;                      // nbl >= M
  const int P = (nbl + KCH - 1) / KCH + 1;        // phases (consumer lags 1 chunk)
  const int hiw = (wv == 1 || wv == 2) ? 64 : 0;  // hi waves read words 64..127
  const uint32* __restrict__ Er =
      reinterpret_cast<const uint32*>(E) + ((size_t)b << 11) * 128 + hiw + lane;
  const float* __restrict__ Ebb = Ebs + (b << 11);

  {  // cooperative blank preload (2048 floats, 4 waves)
    const float4* src = reinterpret_cast<const float4*>(Ebb);
    float4* dst = reinterpret_cast<float4*>(LB);
    for (int i = threadIdx.x; i < 512; i += 256) dst[i] = src[i];
  }
  __syncthreads();

  if (wv == 0) {
    // ================= fwd-lo (producer) : states 4l..4l+3 =================
    const int2 tt = reinterpret_cast<const int2*>(targets + (b << 8))[lane];
    const int prev = __shfl_up(tt.y, 1);
    const bool sk0 = (lane != 0) && (tt.x != prev);
    const bool sk1 = (tt.y != tt.x);
    float a0 = NEGF, a1 = NEGF, a2 = NEGF, a3 = NEGF;
    if (lane == 0) { a0 = LB[2047]; a1 = bf2f_lo(Er[0]); }
    uint32 pf[PG][4]; float4 pb[PG];
    auto fetch = [&](int slot, int g) {
#pragma unroll
      for (int j = 0; j < 4; ++j) {
        int r = 1 + 4 * g + j; r = (r > 2047) ? 2047 : r;
        pf[slot][j] = Er[(size_t)r * 128];
      }
      int kk = (g > 511) ? 511 : g;
      pb[slot] = reinterpret_cast<const float4*>(LB)[kk];
    };
    auto step = [&](uint32 em, float eb) {
      const float e0 = bf2f_lo(em), e1 = bf2f_hi(em);
      const float am1 = dpp_shr1(NEGF, a3);
      const float x0 = fmaxf(a0, am1) + eb;
      const float x1 = fmaxf(fmaxf(a1, a0), sk0 ? am1 : NEGF) + e0;
      const float x2 = fmaxf(a2, a1) + eb;
      const float x3 = fmaxf(fmaxf(a3, a2), sk1 ? a1 : NEGF) + e1;
      a0 = x0; a1 = x1; a2 = x2; a3 = x3;
    };
    const int n = M;
#pragma unroll
    for (int s = 0; s < PG; ++s) fetch(s, s);
    __builtin_amdgcn_sched_barrier(0);
    for (int p = 0; p < P; ++p) {
      float* Bw = Bf[p & 1];
      const int gbase = p * GPP;
#pragma unroll 1
      for (int rev = 0; rev < REVS; ++rev) {
        const int qbase = rev * PG;
#pragma unroll
        for (int s = 0; s < PG; ++s) {
          const int q = qbase + s;
          const int g = gbase + q;
          const int st0 = 4 * g;
          if (st0 < n) {
            float s0 = a3, s1, s2, s3;
            if (st0 + 4 <= n) {
              step(pf[s][0], pb[s].x); s1 = a3;
              step(pf[s][1], pb[s].y); s2 = a3;
              step(pf[s][2], pb[s].z); s3 = a3;
              step(pf[s][3], pb[s].w);
            } else {
              const int rem = n - st0;
              step(pf[s][0], pb[s].x); s1 = a3;
              if (rem > 1) step(pf[s][1], pb[s].y); s2 = a3;
              if (rem > 2) step(pf[s][2], pb[s].z); s3 = a3;
            }
            if (lane == 63) *reinterpret_cast<float4*>(&Bw[4 * q]) = make_float4(s0, s1, s2, s3);
          }
          fetch(s, g + PG);
          __builtin_amdgcn_sched_barrier(0);
        }
      }
      asm volatile("s_waitcnt lgkmcnt(0)" ::: "memory");
      __builtin_amdgcn_sched_barrier(0);
      __builtin_amdgcn_s_barrier();
    }
    // dump barrier (bwd waves publish Bt)
    asm volatile("s_waitcnt lgkmcnt(0)" ::: "memory");
    __builtin_amdgcn_sched_barrier(0);
    __builtin_amdgcn_s_barrier();
    // merge over states 4l..4l+3
    const int t128 = targets[(b << 8) + 128];
    const int nx = __shfl_down(tt.x, 1);
    const bool m1 = (lane == 63) ? (t128 != tt.y) : (nx != tt.y);
    const int s0 = 4 * lane;
    float best;
    best =             a0 + fmaxf(Bt[s0],     Bt[s0 + 1]);
    best = fmaxf(best, a1 + fmaxf(fmaxf(Bt[s0 + 1], Bt[s0 + 2]), sk1 ? Bt[s0 + 3] : NEGF));
    best = fmaxf(best, a2 + fmaxf(Bt[s0 + 2], Bt[s0 + 3]));
    best = fmaxf(best, a3 + fmaxf(fmaxf(Bt[s0 + 3], Bt[s0 + 4]), m1 ? Bt[s0 + 5] : NEGF));
#pragma unroll
    for (int off = 32; off; off >>= 1) best = fmaxf(best, __shfl_down(best, off));
    if (lane == 0) Pm[0] = best;

  } else if (wv == 1) {
    // ================= fwd-hi (consumer) : states 256+4l..+3, +512 =========
    const int2 tt = reinterpret_cast<const int2*>(targets + (b << 8))[64 + lane];
    const int t127 = targets[(b << 8) + 127];
    const int pw = __shfl_up(tt.y, 1);
    const int prevh = (lane == 0) ? t127 : pw;
    const bool skh0 = (tt.x != prevh);            // s-2 = state 255+4l always exists
    const bool skh1 = (tt.y != tt.x);
    float a0 = NEGF, a1 = NEGF, a2 = NEGF, a3 = NEGF, a4 = NEGF;
    uint32 pf[PG][4]; float4 pb[PG];
    auto fetch = [&](int slot, int g) {
#pragma unroll
      for (int j = 0; j < 4; ++j) {
        int r = 1 + 4 * g + j; r = (r > 2047) ? 2047 : r;
        pf[slot][j] = Er[(size_t)r * 128];
      }
      int kk = (g > 511) ? 511 : g;
      pb[slot] = reinterpret_cast<const float4*>(LB)[kk];
    };
    auto step = [&](uint32 em, float eb, float bv) {
      const float e0 = bf2f_lo(em), e1 = bf2f_hi(em);
      const float am1 = dpp_shr1(bv, a3);         // lane0 <- boundary alpha[255]
      const float x0 = fmaxf(a0, am1) + eb;
      const float x1 = fmaxf(fmaxf(a1, a0), skh0 ? am1 : NEGF) + e0;
      const float x2 = fmaxf(a2, a1) + eb;
      const float x3 = fmaxf(fmaxf(a3, a2), skh1 ? a1 : NEGF) + e1;
      const float x4 = fmaxf(a4, a3) + eb;        // state 512 (lane63 only meaningful)
      a0 = x0; a1 = x1; a2 = x2; a3 = x3; a4 = x4;
    };
    const int n = M;
#pragma unroll
    for (int s = 0; s < PG; ++s) fetch(s, s);
    __builtin_amdgcn_sched_barrier(0);
    for (int p = 0; p < P; ++p) {
      if (p >= 1) {
        const float* Bw = Bf[(p - 1) & 1];
        const int gbase = (p - 1) * GPP;
        float4 bvA = reinterpret_cast<const float4*>(Bw)[0], bvB;
#pragma unroll 1
        for (int rev = 0; rev < REVS; ++rev) {
          const int qbase = rev * PG;
#pragma unroll
          for (int s = 0; s < PG; ++s) {
            const int q = qbase + s;
            const int g = gbase + q;
            const int st0 = 4 * g;
            const int qn = (q < GPP - 1) ? (q + 1) : (GPP - 1);
            float4 bv;
            if (!(s & 1)) { bvB = reinterpret_cast<const float4*>(Bw)[qn]; bv = bvA; }
            else          { bvA = reinterpret_cast<const float4*>(Bw)[qn]; bv = bvB; }
            if (st0 < n) {
              if (st0 + 4 <= n) {
                step(pf[s][0], pb[s].x, bv.x);
                step(pf[s][1], pb[s].y, bv.y);
                step(pf[s][2], pb[s].z, bv.z);
                step(pf[s][3], pb[s].w, bv.w);
              } else {
                const int rem = n - st0;
                step(pf[s][0], pb[s].x, bv.x);
                if (rem > 1) step(pf[s][1], pb[s].y, bv.y);
                if (rem > 2) step(pf[s][2], pb[s].z, bv.z);
              }
            }
            fetch(s, g + PG);
            __builtin_amdgcn_sched_barrier(0);
          }
        }
      }
      asm volatile("s_waitcnt lgkmcnt(0)" ::: "memory");
      __builtin_amdgcn_sched_barrier(0);
      __builtin_amdgcn_s_barrier();
    }
    asm volatile("s_waitcnt lgkmcnt(0)" ::: "memory");
    __builtin_amdgcn_sched_barrier(0);
    __builtin_amdgcn_s_barrier();
    // merge over states 256+4l..+3 (+512)
    const int nxh = __shfl_down(tt.x, 1);
    const bool m1 = (lane < 63) && (nxh != tt.y);
    const int s0 = 256 + 4 * lane;
    float best;
    best =             a0 + fmaxf(Bt[s0],     Bt[s0 + 1]);
    best = fmaxf(best, a1 + fmaxf(fmaxf(Bt[s0 + 1], Bt[s0 + 2]), skh1 ? Bt[s0 + 3] : NEGF));
    best = fmaxf(best, a2 + fmaxf(Bt[s0 + 2], Bt[s0 + 3]));
    best = fmaxf(best, a3 + fmaxf(fmaxf(Bt[s0 + 3], Bt[s0 + 4]), m1 ? Bt[s0 + 5] : NEGF));
    best = fmaxf(best, (lane == 63) ? (a4 + Bt[512]) : NEGF);
#pragma unroll
    for (int off = 32; off; off >>= 1) best = fmaxf(best, __shfl_down(best, off));
    if (lane == 0) Pm[1] = best;

  } else if (wv == 2) {
    // ================= bwd-hi (producer) : states 256+4l..+3, +512 =========
    const int2 tt = reinterpret_cast<const int2*>(targets + (b << 8))[64 + lane];
    const int nxh = __shfl_down(tt.x, 1);
    const bool kb0 = (tt.y != tt.x);
    const bool kb1 = (lane < 63) && (nxh != tt.y);
    float h0, h1, h2, h3, h4;
    {
      const uint32 er = Er[(size_t)(L - 1) * 128];
      const float e0 = bf2f_lo(er), e1 = bf2f_hi(er);
      const float blankL = LB[L - 2];
      const int s0h = 256 + 4 * lane, tb2 = 2 * tl, tm = 2 * tl - 1;
      h0 = (s0h     == tb2) ? blankL : NEGF;
      h1 = (s0h + 1 == tm ) ? e0     : NEGF;
      h2 = (s0h + 2 == tb2) ? blankL : NEGF;
      h3 = (s0h + 3 == tm ) ? e1     : NEGF;
      h4 = ((lane == 63) && (tb2 == 512)) ? blankL : NEGF;
    }
    uint32 qf[PG][4]; float qb[PG][4];
    auto fetch = [&](int slot, int g) {
#pragma unroll
      for (int j = 0; j < 4; ++j) {
        int r = L - 2 - 4 * g - j; r = (r < 1) ? 1 : r;
        qf[slot][j] = Er[(size_t)r * 128];
        qb[slot][j] = LB[r - 1];
      }
    };
    auto step = [&](uint32 em, float eb) {
      const float e0 = bf2f_lo(em), e1 = bf2f_hi(em);
      const float bn0 = dpp_shl1(h4, h0);
      const float bn1 = dpp_shl1(NEGF, h1);
      const float y0 = fmaxf(h0, h1) + eb;
      const float y1 = fmaxf(fmaxf(h1, h2), kb0 ? h3 : NEGF) + e0;
      const float y2 = fmaxf(h2, h3) + eb;
      const float y3 = fmaxf(fmaxf(h3, bn0), kb1 ? bn1 : NEGF) + e1;
      const float y4 = h4 + eb;
      h0 = y0; h1 = y1; h2 = y2; h3 = y3; h4 = y4;
    };
    const int n = nbl;
#pragma unroll
    for (int s = 0; s < PG; ++s) fetch(s, s);
    __builtin_amdgcn_sched_barrier(0);
    for (int p = 0; p < P; ++p) {
      float* Bw0 = Bb0[p & 1];
      float* Bw1 = Bb1[p & 1];
      const int gbase = p * GPP;
#pragma unroll 1
      for (int rev = 0; rev < REVS; ++rev) {
        const int qbase = rev * PG;
#pragma unroll
        for (int s = 0; s < PG; ++s) {
          const int q = qbase + s;
          const int g = gbase + q;
          const int st0 = 4 * g;
          if (st0 < n) {
            float u0 = h0, v0 = h1, u1, v1, u2, v2, u3, v3;
            if (st0 + 4 <= n) {
              step(qf[s][0], qb[s][0]); u1 = h0; v1 = h1;
              step(qf[s][1], qb[s][1]); u2 = h0; v2 = h1;
              step(qf[s][2], qb[s][2]); u3 = h0; v3 = h1;
              step(qf[s][3], qb[s][3]);
            } else {
              const int rem = n - st0;
              step(qf[s][0], qb[s][0]); u1 = h0; v1 = h1;
              if (rem > 1) step(qf[s][1], qb[s][1]); u2 = h0; v2 = h1;
              if (rem > 2) step(qf[s][2], qb[s][2]); u3 = h0; v3 = h1;
            }
            if (lane == 0) {
              *reinterpret_cast<float4*>(&Bw0[4 * q]) = make_float4(u0, u1, u2, u3);
              *reinterpret_cast<float4*>(&Bw1[4 * q]) = make_float4(v0, v1, v2, v3);
            }
          }
          fetch(s, g + PG);
          __builtin_amdgcn_sched_barrier(0);
        }
      }
      asm volatile("s_waitcnt lgkmcnt(0)" ::: "memory");
      __builtin_amdgcn_sched_barrier(0);
      __builtin_amdgcn_s_barrier();
    }
    Bt[256 + 4 * lane + 0] = h0; Bt[256 + 4 * lane + 1] = h1;
    Bt[256 + 4 * lane + 2] = h2; Bt[256 + 4 * lane + 3] = h3;
    if (lane == 63) Bt[512] = h4;
    if (lane == 0) { Bt[513] = NEGF; Bt[514] = NEGF; }
    asm volatile("s_waitcnt lgkmcnt(0)" ::: "memory");
    __builtin_amdgcn_sched_barrier(0);
    __builtin_amdgcn_s_barrier();

  } else {
    // ================= bwd-lo (consumer) : states 4l..4l+3 =================
    const int2 tt = reinterpret_cast<const int2*>(targets + (b << 8))[lane];
    const int t128 = targets[(b << 8) + 128];
    const int nx = __shfl_down(tt.x, 1);
    const bool kb0 = (tt.y != tt.x);
    const bool kb1 = (lane == 63) ? (t128 != tt.y) : (nx != tt.y);
    float h0, h1, h2, h3;
    {
      const uint32 er = Er[(size_t)(L - 1) * 128];
      const float e0 = bf2f_lo(er), e1 = bf2f_hi(er);
      const float blankL = LB[L - 2];
      const int s0 = 4 * lane, tb2 = 2 * tl, tm = 2 * tl - 1;
      h0 = (s0     == tb2) ? blankL : NEGF;
      h1 = (s0 + 1 == tm ) ? e0     : NEGF;
      h2 = (s0 + 2 == tb2) ? blankL : NEGF;
      h3 = (s0 + 3 == tm ) ? e1     : NEGF;
    }
    uint32 qf[PG][4]; float qb[PG][4];
    auto fetch = [&](int slot, int g) {
#pragma unroll
      for (int j = 0; j < 4; ++j) {
        int r = L - 2 - 4 * g - j; r = (r < 1) ? 1 : r;
        qf[slot][j] = Er[(size_t)r * 128];
        qb[slot][j] = LB[r - 1];
      }
    };
    auto step = [&](uint32 em, float eb, float bv0, float bv1) {
      const float e0 = bf2f_lo(em), e1 = bf2f_hi(em);
      const float bn0 = dpp_shl1(bv0, h0);        // lane63 <- beta[256]
      const float bn1 = dpp_shl1(bv1, h1);        // lane63 <- beta[257]
      const float y0 = fmaxf(h0, h1) + eb;
      const float y1 = fmaxf(fmaxf(h1, h2), kb0 ? h3 : NEGF) + e0;
      const float y2 = fmaxf(h2, h3) + eb;
      const float y3 = fmaxf(fmaxf(h3, bn0), kb1 ? bn1 : NEGF) + e1;
      h0 = y0; h1 = y1; h2 = y2; h3 = y3;
    };
    const int n = nbl;
#pragma unroll
    for (int s = 0; s < PG; ++s) fetch(s, s);
    __builtin_amdgcn_sched_barrier(0);
    for (int p = 0; p < P; ++p) {
      if (p >= 1) {
        const float* Bw0 = Bb0[(p - 1) & 1];
        const float* Bw1 = Bb1[(p - 1) & 1];
        const int gbase = (p - 1) * GPP;
        float4 b0A = reinterpret_cast<const float4*>(Bw0)[0], b0B;
        float4 b1A = reinterpret_cast<const float4*>(Bw1)[0], b1B;
#pragma unroll 1
        for (int rev = 0; rev < REVS; ++rev) {
          const int qbase = rev * PG;
#pragma unroll
          for (int s = 0; s < PG; ++s) {
            const int q = qbase + s;
            const int g = gbase + q;
            const int st0 = 4 * g;
            const int qn = (q < GPP - 1) ? (q + 1) : (GPP - 1);
            float4 c0, c1;
            if (!(s & 1)) {
              b0B = reinterpret_cast<const float4*>(Bw0)[qn];
              b1B = reinterpret_cast<const float4*>(Bw1)[qn];
              c0 = b0A; c1 = b1A;
            } else {
              b0A = reinterpret_cast<const float4*>(Bw0)[qn];
              b1A = reinterpret_cast<const float4*>(Bw1)[qn];
              c0 = b0B; c1 = b1B;
            }
            if (st0 < n) {
              if (st0 + 4 <= n) {
                step(qf[s][0], qb[s][0], c0.x, c1.x);
                step(qf[s][1], qb[s][1], c0.y, c1.y);
                step(qf[s][2], qb[s][2], c0.z, c1.z);
                step(qf[s][3], qb[s][3], c0.w, c1.w);
              } else {
                const int rem = n - st0;
                step(qf[s][0], qb[s][0], c0.x, c1.x);
                if (rem > 1) step(qf[s][1], qb[s][1], c0.y, c1.y);
                if (rem > 2) step(qf[s][2], qb[s][2], c0.z, c1.z);
              }
            }
            fetch(s, g + PG);
            __builtin_amdgcn_sched_barrier(0);
          }
        }
      }
      asm volatile("s_waitcnt lgkmcnt(0)" ::: "memory");
      __builtin_amdgcn_sched_barrier(0);
      __builtin_amdgcn_s_barrier();
    }
    Bt[4 * lane + 0] = h0; Bt[4 * lane + 1] = h1;
    Bt[4 * lane + 2] = h2; Bt[4 * lane + 3] = h3;
    asm volatile("s_waitcnt lgkmcnt(0)" ::: "memory");
    __builtin_amdgcn_sched_barrier(0);
    __builtin_amdgcn_s_barrier();
  }

  __syncthreads();
  if (threadIdx.x == 0) vpart[b] = fmaxf(Pm[0], Pm[1]);
}

// ---------------------------------------------------------------------------
// Kernel C: out = (sum(gpart) - sum(vpart)) / sum(L_b)
// ---------------------------------------------------------------------------
__global__ __launch_bounds__(256) void finalize_kernel(
    const int* __restrict__ llen, const float* __restrict__ gpart,
    const float* __restrict__ vpart, float* __restrict__ out) {
  __shared__ float sred[4], lred[4];
  const int t = threadIdx.x, lane = t & 63, w = t >> 6;
  float s = 0.f;
#pragma unroll
  for (int i = 0; i < 8; ++i) s += gpart[t + (i << 8)];
  float lf = 0.f;
  if (t < 64) { s -= vpart[t]; lf = (float)llen[t]; }
#pragma unroll
  for (int off = 32; off; off >>= 1) {
    s += __shfl_down(s, off);
    lf += __shfl_down(lf, off);
  }
  if (lane == 0) { sred[w] = s; lred[w] = lf; }
  __syncthreads();
  if (t == 0)
    out[0] = (sred[0] + sred[1] + sred[2] + sred[3]) /
             (lred[0] + lred[1] + lred[2] + lred[3]);
}

extern "C" void kernel_launch(void* const* d_in, const int* in_sizes, int n_in,
                              void* d_out, int out_size, void* d_ws, size_t ws_size,
                              hipStream_t stream) {
  const float* logits  = (const float*)d_in[0];   // [B,T,V] fp32
  const int*   targets = (const int*)d_in[1];     // [B,U] int32
  const int*   llen    = (const int*)d_in[2];     // [B]
  const int*   tlen    = (const int*)d_in[3];     // [B]
  float* out = (float*)d_out;

  // ws layout: [0,8K) gpart[2048] | [8K,8K+256) vpart[64] |
  //            [16384, +512K) Ebs fp32 | [1MiB, +64MiB) E bf16
  float*          gpart = (float*)d_ws;
  float*          vpart = (float*)d_ws + 2048;
  float*          Ebs   = (float*)((char*)d_ws + 16384);
  unsigned short* E     = (unsigned short*)((char*)d_ws + (1u << 20));

  gather_lse_kernel<<<Bb * 32, 256, 0, stream>>>(logits, targets, llen, gpart, Ebs, E);
  viterbi_kernel<<<Bb, 256, 0, stream>>>(E, Ebs, targets, llen, tlen, vpart);
  finalize_kernel<<<1, 256, 0, stream>>>(llen, gpart, vpart, out);
}

// Round 4
// 275.751 us; speedup vs baseline: 1.2336x; 1.0426x over previous
//
#include <hip/hip_runtime.h>

#define NEGF -1e30f
typedef unsigned int uint32;

static constexpr int Bb = 64, Tt = 2048, Vv = 256, Uu = 256;
// S = 2*U+1 = 513 states; lane l owns states 8l..8l+7 (+512 on lane 63).
// Ebs layout (per batch, 2048 floats): Ebs[i] = blank[i+1] for i=0..2046,
// Ebs[2047] = blank[0].
// R11 = R7's proven two-wave viterbi (81us, rings fully in VGPRs at 124 regs)
// + R10's memset-free launch structure (plain-store partials, ~31us measured
// outside viterbi). R9/R10 state-split retired: slot reduction never showed
// up as time (~12 cyc/slot vs R7's 5.4, cause not isolated; R10 also spilled
// its PG=8 ring - VGPR_Count 56 < ~75 needed).

__device__ __forceinline__ unsigned short f2bf(float f) {    // RNE, no NaN inputs
  uint32 u = __builtin_bit_cast(uint32, f);
  u += 0x7fffu + ((u >> 16) & 1u);
  return (unsigned short)(u >> 16);
}
__device__ __forceinline__ float bf2f_lo(uint32 p) { return __builtin_bit_cast(float, p << 16); }
__device__ __forceinline__ float bf2f_hi(uint32 p) { return __builtin_bit_cast(float, p & 0xffff0000u); }

// DPP cross-lane, gfx9-family wave-level shifts (1 VALU op, no LDS):
// wave_shr:1 (0x138): lane l <- lane l-1; lane 0 keeps `old` (bound_ctrl=0).
// wave_shl:1 (0x130): lane l <- lane l+1; lane 63 keeps `old`.
__device__ __forceinline__ float dpp_shr1(float old, float src) {
  return __builtin_bit_cast(float, __builtin_amdgcn_update_dpp(
      __builtin_bit_cast(int, old), __builtin_bit_cast(int, src), 0x138, 0xF, 0xF, false));
}
__device__ __forceinline__ float dpp_shl1(float old, float src) {
  return __builtin_bit_cast(float, __builtin_amdgcn_update_dpp(
      __builtin_bit_cast(int, old), __builtin_bit_cast(int, src), 0x130, 0xF, 0xF, false));
}

// ---------------------------------------------------------------------------
// Kernel A: one streaming pass over logits; 8 rows in flight per wave.
//   - gpart[block] = partial sum of logsumexp over valid frames (plain store)
//   - E[b][t][u] = bf16(logits[b][t][targets[b][u]]), t < L only
//   - Ebs shifted-blank array
// ---------------------------------------------------------------------------
__global__ __launch_bounds__(256) void gather_lse_kernel(
    const float* __restrict__ logits, const int* __restrict__ targets,
    const int* __restrict__ llen, float* __restrict__ gpart,
    float* __restrict__ Ebs, unsigned short* __restrict__ E) {
  __shared__ __align__(16) float buf[4][8][Vv];   // 32 KB
  __shared__ float wpart[4];
  const int b = blockIdx.x >> 5;
  const int c = blockIdx.x & 31;
  const int w = threadIdx.x >> 6;
  const int lane = threadIdx.x & 63;
  const int L = llen[b];
  const int4 lb = reinterpret_cast<const int4*>(targets + (b << 8))[lane];
  const float* __restrict__ lgb = logits + (size_t)b * (Tt * Vv);
  float lse_local = 0.f;
#pragma unroll
  for (int k = 0; k < 2; ++k) {
    const int tbase = (c << 6) + (k << 5) + w;    // rows tbase + 4j, j=0..7
    if (tbase >= L) break;                        // wave-uniform
    float4 v[8];
#pragma unroll
    for (int j = 0; j < 8; ++j)
      v[j] = reinterpret_cast<const float4*>(lgb + (size_t)(tbase + 4 * j) * Vv)[lane];
    float s[8];
#pragma unroll
    for (int j = 0; j < 8; ++j)
      s[j] = __expf(v[j].x) + __expf(v[j].y) + __expf(v[j].z) + __expf(v[j].w);
#pragma unroll
    for (int off = 32; off; off >>= 1) {
#pragma unroll
      for (int j = 0; j < 8; ++j) s[j] += __shfl_down(s[j], off);
    }
#pragma unroll
    for (int j = 0; j < 8; ++j)
      reinterpret_cast<float4*>(&buf[w][j][0])[lane] = v[j];
#pragma unroll
    for (int j = 0; j < 8; ++j) {                 // intra-wave DS ordering
      const int t = tbase + 4 * j;
      const bool val = t < L;
      ushort4 o;
      o.x = f2bf(buf[w][j][lb.x]); o.y = f2bf(buf[w][j][lb.y]);
      o.z = f2bf(buf[w][j][lb.z]); o.w = f2bf(buf[w][j][lb.w]);
      if (val)
        reinterpret_cast<ushort4*>(E + ((size_t)((b << 11) + t)) * Vv)[lane] = o;
      if ((lane == 0) & val) {
        lse_local += __logf(s[j]);
        Ebs[(b << 11) + ((t == 0) ? 2047 : t - 1)] = v[j].x;   // row[0] = blank
      }
    }
  }
  if (lane == 0) wpart[w] = lse_local;
  __syncthreads();
  if (threadIdx.x == 0)
    gpart[blockIdx.x] = wpart[0] + wpart[1] + wpart[2] + wpart[3];
}

// ---------------------------------------------------------------------------
// Kernel B: bidirectional max-plus Viterbi, 2 waves per batch (R7 structure).
//   wave0: alpha forward t=0..M (em-inclusive), M=(L-2)>>1
//   wave1: beta backward t=L-1..M+1
//   merge: vpart[b] = max_s alpha[M][s] + max(beta[s], beta[s+1], skip? beta[s+2])
// R5 register-ring structure (PG=8 groups x 4 rows, sched_barrier-pinned) with
// the per-step cross-lane op done via DPP wave shifts.
// ---------------------------------------------------------------------------
#define PG 8
__global__ __launch_bounds__(128) void viterbi_kernel(
    const unsigned short* __restrict__ E, const float* __restrict__ Ebs,
    const int* __restrict__ targets, const int* __restrict__ llen,
    const int* __restrict__ tlen, float* __restrict__ vpart) {
  __shared__ __align__(16) float LB[2048];   // blanks (shifted layout), 8 KB
  __shared__ float Bt[520];
  const int b = blockIdx.x;
  const int lane = threadIdx.x & 63;
  const int wv = threadIdx.x >> 6;
  const int L = llen[b];
  const int tl = tlen[b];
  const int M = (L - 2) >> 1;
  const int4 lb = reinterpret_cast<const int4*>(targets + (b << 8))[lane];
  const uint2* __restrict__ Erow = reinterpret_cast<const uint2*>(E) + ((size_t)(b << 11) << 6);
  const float* __restrict__ Ebb = Ebs + (b << 11);

  // cooperative blank preload: 2048 floats
  {
    const float4* src = reinterpret_cast<const float4*>(Ebb);
    float4* dst = reinterpret_cast<float4*>(LB);
    for (int i = threadIdx.x; i < 512; i += 128) dst[i] = src[i];
  }
  __syncthreads();

  float a0 = NEGF, a1 = NEGF, a2 = NEGF, a3 = NEGF, a4 = NEGF,
        a5 = NEGF, a6 = NEGF, a7 = NEGF, a8 = NEGF;

  if (wv == 0) {
    // ---------------- forward wave ----------------
    const int prevw = __shfl_up(lb.w, 1);
    const bool sk0 = (lane != 0) && (lb.x != prevw);
    const bool sk1 = (lb.y != lb.x);
    const bool sk2 = (lb.z != lb.y);
    const bool sk3 = (lb.w != lb.z);
    if (lane == 0) {
      a0 = LB[2047];                                            // blank[0]
      a1 = bf2f_lo((uint32)*reinterpret_cast<const unsigned short*>(E + ((size_t)(b << 11) << 8)));
    }
    uint2 pf[PG][4];
    float4 pb[PG];
    auto fetchf = [&](int slot, int k) {
      const int kk = (k > 511) ? 511 : k;
#pragma unroll
      for (int j = 0; j < 4; ++j) {
        int r = 1 + 4 * kk + j; r = (r > 2047) ? 2047 : r;
        pf[slot][j] = Erow[(size_t)(r << 6) + lane];
      }
      pb[slot] = reinterpret_cast<const float4*>(LB)[kk];       // blank[4kk+1..4kk+4]
    };
    auto stepf = [&](uint2 em, float eb) {
      const float e0 = bf2f_lo(em.x), e1 = bf2f_hi(em.x);
      const float e2 = bf2f_lo(em.y), e3 = bf2f_hi(em.y);
      const float am1 = dpp_shr1(NEGF, a7);                     // lane0 -> NEGF
      const float x0 = fmaxf(a0, am1) + eb;
      const float x1 = fmaxf(fmaxf(a1, a0), sk0 ? am1 : NEGF) + e0;
      const float x2 = fmaxf(a2, a1) + eb;
      const float x3 = fmaxf(fmaxf(a3, a2), sk1 ? a1 : NEGF) + e1;
      const float x4 = fmaxf(a4, a3) + eb;
      const float x5 = fmaxf(fmaxf(a5, a4), sk2 ? a3 : NEGF) + e2;
      const float x6 = fmaxf(a6, a5) + eb;
      const float x7 = fmaxf(fmaxf(a7, a6), sk3 ? a5 : NEGF) + e3;
      const float x8 = fmaxf(a8, a7) + eb;
      a0 = x0; a1 = x1; a2 = x2; a3 = x3; a4 = x4; a5 = x5; a6 = x6; a7 = x7; a8 = x8;
    };
    const int n = M, Gf = n >> 2, remf = n & 3;
#pragma unroll
    for (int s = 0; s < PG; ++s) fetchf(s, s);
    __builtin_amdgcn_sched_barrier(0);
    int g = 0;
    while (g + PG <= Gf) {
#pragma unroll
      for (int s = 0; s < PG; ++s) {
#pragma unroll
        for (int j = 0; j < 4; ++j) stepf(pf[s][j], (&pb[s].x)[j]);
        fetchf(s, g + s + PG);
        __builtin_amdgcn_sched_barrier(0);
      }
      g += PG;
    }
    const int left = Gf - g;   // 0..PG-1
#pragma unroll
    for (int s = 0; s < PG; ++s) {
      if (s < left) {
#pragma unroll
        for (int j = 0; j < 4; ++j) stepf(pf[s][j], (&pb[s].x)[j]);
      }
    }
#pragma unroll
    for (int s = 0; s < PG; ++s) {
      if (s == left) {
#pragma unroll
        for (int j = 0; j < 4; ++j)
          if (j < remf) stepf(pf[s][j], (&pb[s].x)[j]);
      }
    }
  } else {
    // ---------------- backward wave ----------------
    const int nlabx = __shfl_down(lb.x, 1);
    const bool kb0 = (lb.y != lb.x);
    const bool kb1 = (lb.z != lb.y);
    const bool kb2 = (lb.w != lb.z);
    const bool kb3 = (lane < 63) && (nlabx != lb.w);
    {
      const uint2 er = Erow[(size_t)((L - 1) << 6) + lane];
      const float e0 = bf2f_lo(er.x), e1 = bf2f_hi(er.x);
      const float e2 = bf2f_lo(er.y), e3 = bf2f_hi(er.y);
      const float blankL = LB[L - 2];                           // blank[L-1]
      const int s0 = 8 * lane, tb = 2 * tl, tm = 2 * tl - 1;
      a0 = (s0     == tb) ? blankL : NEGF;
      a1 = (s0 + 1 == tm) ? e0     : NEGF;
      a2 = (s0 + 2 == tb) ? blankL : NEGF;
      a3 = (s0 + 3 == tm) ? e1     : NEGF;
      a4 = (s0 + 4 == tb) ? blankL : NEGF;
      a5 = (s0 + 5 == tm) ? e2     : NEGF;
      a6 = (s0 + 6 == tb) ? blankL : NEGF;
      a7 = (s0 + 7 == tm) ? e3     : NEGF;
      a8 = ((lane == 63) && (tb == 512)) ? blankL : NEGF;
    }
    uint2 qf[PG][4];
    float qb[PG][4];
    auto fetchb = [&](int slot, int k) {
#pragma unroll
      for (int j = 0; j < 4; ++j) {
        int r = L - 2 - 4 * k - j; r = (r < 1) ? 1 : r;
        qf[slot][j] = Erow[(size_t)(r << 6) + lane];
        qb[slot][j] = LB[r - 1];                                // blank[r]
      }
    };
    auto stepb = [&](uint2 em, float eb) {
      const float e0 = bf2f_lo(em.x), e1 = bf2f_hi(em.x);
      const float e2 = bf2f_lo(em.y), e3 = bf2f_hi(em.y);
      const float bn0 = dpp_shl1(a8, a0);     // lane l: a0[l+1]; lane63: own a8
      const float bn1 = dpp_shl1(NEGF, a1);   // lane l: a1[l+1]; lane63: NEGF
      const float y0 = fmaxf(a0, a1) + eb;
      const float y1 = fmaxf(fmaxf(a1, a2), kb0 ? a3 : NEGF) + e0;
      const float y2 = fmaxf(a2, a3) + eb;
      const float y3 = fmaxf(fmaxf(a3, a4), kb1 ? a5 : NEGF) + e1;
      const float y4 = fmaxf(a4, a5) + eb;
      const float y5 = fmaxf(fmaxf(a5, a6), kb2 ? a7 : NEGF) + e2;
      const float y6 = fmaxf(a6, a7) + eb;
      const float y7 = fmaxf(fmaxf(a7, bn0), kb3 ? bn1 : NEGF) + e3;
      const float y8 = a8 + eb;
      a0 = y0; a1 = y1; a2 = y2; a3 = y3; a4 = y4; a5 = y5; a6 = y6; a7 = y7; a8 = y8;
    };
    const int n = L - 2 - M, Gb = n >> 2, remb = n & 3;
#pragma unroll
    for (int s = 0; s < PG; ++s) fetchb(s, s);
    __builtin_amdgcn_sched_barrier(0);
    int g = 0;
    while (g + PG <= Gb) {
#pragma unroll
      for (int s = 0; s < PG; ++s) {
#pragma unroll
        for (int j = 0; j < 4; ++j) stepb(qf[s][j], qb[s][j]);
        fetchb(s, g + s + PG);
        __builtin_amdgcn_sched_barrier(0);
      }
      g += PG;
    }
    const int left = Gb - g;
#pragma unroll
    for (int s = 0; s < PG; ++s) {
      if (s < left) {
#pragma unroll
        for (int j = 0; j < 4; ++j) stepb(qf[s][j], qb[s][j]);
      }
    }
#pragma unroll
    for (int s = 0; s < PG; ++s) {
      if (s == left) {
#pragma unroll
        for (int j = 0; j < 4; ++j)
          if (j < remb) stepb(qf[s][j], qb[s][j]);
      }
    }
    // dump beta[M+1] to LDS (+NEG padding)
    Bt[8 * lane + 0] = a0; Bt[8 * lane + 1] = a1;
    Bt[8 * lane + 2] = a2; Bt[8 * lane + 3] = a3;
    Bt[8 * lane + 4] = a4; Bt[8 * lane + 5] = a5;
    Bt[8 * lane + 6] = a6; Bt[8 * lane + 7] = a7;
    if (lane == 63) Bt[512] = a8;
    if (lane == 0) { Bt[513] = NEGF; Bt[514] = NEGF; }
  }
  __syncthreads();
  if (wv == 0) {
    const int nlabx = __shfl_down(lb.x, 1);
    const bool kb0 = (lb.y != lb.x);
    const bool kb1 = (lb.z != lb.y);
    const bool kb2 = (lb.w != lb.z);
    const bool kb3 = (lane < 63) && (nlabx != lb.w);
    const int s0 = 8 * lane;
    float best;
    best =             a0 + fmaxf(Bt[s0],     Bt[s0 + 1]);
    best = fmaxf(best, a1 + fmaxf(fmaxf(Bt[s0 + 1], Bt[s0 + 2]), kb0 ? Bt[s0 + 3] : NEGF));
    best = fmaxf(best, a2 + fmaxf(Bt[s0 + 2], Bt[s0 + 3]));
    best = fmaxf(best, a3 + fmaxf(fmaxf(Bt[s0 + 3], Bt[s0 + 4]), kb1 ? Bt[s0 + 5] : NEGF));
    best = fmaxf(best, a4 + fmaxf(Bt[s0 + 4], Bt[s0 + 5]));
    best = fmaxf(best, a5 + fmaxf(fmaxf(Bt[s0 + 5], Bt[s0 + 6]), kb2 ? Bt[s0 + 7] : NEGF));
    best = fmaxf(best, a6 + fmaxf(Bt[s0 + 6], Bt[s0 + 7]));
    best = fmaxf(best, a7 + fmaxf(fmaxf(Bt[s0 + 7], Bt[s0 + 8]), kb3 ? Bt[s0 + 9] : NEGF));
    best = fmaxf(best, a8 + Bt[512]);
#pragma unroll
    for (int off = 32; off; off >>= 1) best = fmaxf(best, __shfl_down(best, off));
    if (lane == 0) vpart[b] = best;
  }
}

// ---------------------------------------------------------------------------
// Kernel C: out = (sum(gpart) - sum(vpart)) / sum(L_b)
// ---------------------------------------------------------------------------
__global__ __launch_bounds__(256) void finalize_kernel(
    const int* __restrict__ llen, const float* __restrict__ gpart,
    const float* __restrict__ vpart, float* __restrict__ out) {
  __shared__ float sred[4], lred[4];
  const int t = threadIdx.x, lane = t & 63, w = t >> 6;
  float s = 0.f;
#pragma unroll
  for (int i = 0; i < 8; ++i) s += gpart[t + (i << 8)];
  float lf = 0.f;
  if (t < 64) { s -= vpart[t]; lf = (float)llen[t]; }
#pragma unroll
  for (int off = 32; off; off >>= 1) {
    s += __shfl_down(s, off);
    lf += __shfl_down(lf, off);
  }
  if (lane == 0) { sred[w] = s; lred[w] = lf; }
  __syncthreads();
  if (t == 0)
    out[0] = (sred[0] + sred[1] + sred[2] + sred[3]) /
             (lred[0] + lred[1] + lred[2] + lred[3]);
}

extern "C" void kernel_launch(void* const* d_in, const int* in_sizes, int n_in,
                              void* d_out, int out_size, void* d_ws, size_t ws_size,
                              hipStream_t stream) {
  const float* logits  = (const float*)d_in[0];   // [B,T,V] fp32
  const int*   targets = (const int*)d_in[1];     // [B,U] int32
  const int*   llen    = (const int*)d_in[2];     // [B]
  const int*   tlen    = (const int*)d_in[3];     // [B]
  float* out = (float*)d_out;

  // ws layout: [0,8K) gpart[2048] | [8K,8K+256) vpart[64] |
  //            [16384, +512K) Ebs fp32 | [1MiB, +64MiB) E bf16
  float*          gpart = (float*)d_ws;
  float*          vpart = (float*)d_ws + 2048;
  float*          Ebs   = (float*)((char*)d_ws + 16384);
  unsigned short* E     = (unsigned short*)((char*)d_ws + (1u << 20));

  gather_lse_kernel<<<Bb * 32, 256, 0, stream>>>(logits, targets, llen, gpart, Ebs, E);
  viterbi_kernel<<<Bb, 128, 0, stream>>>(E, Ebs, targets, llen, tlen, vpart);
  finalize_kernel<<<1, 256, 0, stream>>>(llen, gpart, vpart, out);
}

// Round 5
// 260.402 us; speedup vs baseline: 1.3063x; 1.0589x over previous
//
#include <hip/hip_runtime.h>

#define NEGF -1e30f
typedef unsigned int uint32;

static constexpr int Bb = 64, Tt = 2048, Vv = 256, Uu = 256;
// S = 2*U+1 = 513 states; lane l owns states 8l..8l+7 (+512 on lane 63).
// Ebs layout (per batch, 2048 floats): Ebs[i] = blank[i+1] for i=0..2046,
// Ebs[2047] = blank[0].
// R12: potential-shift Viterbi. E stores bf16(logit[label] - logit[blank]);
// alpha/beta are tracked minus the running blank sum, so blank states update
// with a pure max (no add) and the blank array never enters the inner loop.
// Compensation Sum(blank[0..L-1]) is added once at the merge.
// Cadence model (R7/R8): per-wave issue ~4.85 cyc/instr regardless of ILP ->
// time == slots/step; this cuts ~8 slots/step from R7's ~39.

__device__ __forceinline__ unsigned short f2bf(float f) {    // RNE, no NaN inputs
  uint32 u = __builtin_bit_cast(uint32, f);
  u += 0x7fffu + ((u >> 16) & 1u);
  return (unsigned short)(u >> 16);
}
__device__ __forceinline__ float bf2f_lo(uint32 p) { return __builtin_bit_cast(float, p << 16); }
__device__ __forceinline__ float bf2f_hi(uint32 p) { return __builtin_bit_cast(float, p & 0xffff0000u); }

// DPP cross-lane, gfx9-family wave-level shifts (1 VALU op, no LDS):
// wave_shr:1 (0x138): lane l <- lane l-1; lane 0 keeps `old` (bound_ctrl=0).
// wave_shl:1 (0x130): lane l <- lane l+1; lane 63 keeps `old`.
__device__ __forceinline__ float dpp_shr1(float old, float src) {
  return __builtin_bit_cast(float, __builtin_amdgcn_update_dpp(
      __builtin_bit_cast(int, old), __builtin_bit_cast(int, src), 0x138, 0xF, 0xF, false));
}
__device__ __forceinline__ float dpp_shl1(float old, float src) {
  return __builtin_bit_cast(float, __builtin_amdgcn_update_dpp(
      __builtin_bit_cast(int, old), __builtin_bit_cast(int, src), 0x130, 0xF, 0xF, false));
}

// ---------------------------------------------------------------------------
// Kernel A: one streaming pass over logits; 8 rows in flight per wave.
//   - gpart[block] = partial sum of logsumexp over valid frames (plain store)
//   - E[b][t][u] = bf16(logits[b][t][targets[b][u]] - logits[b][t][0]), t < L
//   - Ebs shifted-blank array (raw blanks, for compensation + LB)
// ---------------------------------------------------------------------------
__global__ __launch_bounds__(256) void gather_lse_kernel(
    const float* __restrict__ logits, const int* __restrict__ targets,
    const int* __restrict__ llen, float* __restrict__ gpart,
    float* __restrict__ Ebs, unsigned short* __restrict__ E) {
  __shared__ __align__(16) float buf[4][8][Vv];   // 32 KB
  __shared__ float wpart[4];
  const int b = blockIdx.x >> 5;
  const int c = blockIdx.x & 31;
  const int w = threadIdx.x >> 6;
  const int lane = threadIdx.x & 63;
  const int L = llen[b];
  const int4 lb = reinterpret_cast<const int4*>(targets + (b << 8))[lane];
  const float* __restrict__ lgb = logits + (size_t)b * (Tt * Vv);
  float lse_local = 0.f;
#pragma unroll
  for (int k = 0; k < 2; ++k) {
    const int tbase = (c << 6) + (k << 5) + w;    // rows tbase + 4j, j=0..7
    if (tbase >= L) break;                        // wave-uniform
    float4 v[8];
#pragma unroll
    for (int j = 0; j < 8; ++j)
      v[j] = reinterpret_cast<const float4*>(lgb + (size_t)(tbase + 4 * j) * Vv)[lane];
    float s[8];
#pragma unroll
    for (int j = 0; j < 8; ++j)
      s[j] = __expf(v[j].x) + __expf(v[j].y) + __expf(v[j].z) + __expf(v[j].w);
#pragma unroll
    for (int off = 32; off; off >>= 1) {
#pragma unroll
      for (int j = 0; j < 8; ++j) s[j] += __shfl_down(s[j], off);
    }
#pragma unroll
    for (int j = 0; j < 8; ++j)
      reinterpret_cast<float4*>(&buf[w][j][0])[lane] = v[j];
#pragma unroll
    for (int j = 0; j < 8; ++j) {                 // intra-wave DS ordering
      const int t = tbase + 4 * j;
      const bool val = t < L;
      const float bl = buf[w][j][0];              // blank of this row (broadcast)
      ushort4 o;
      o.x = f2bf(buf[w][j][lb.x] - bl); o.y = f2bf(buf[w][j][lb.y] - bl);
      o.z = f2bf(buf[w][j][lb.z] - bl); o.w = f2bf(buf[w][j][lb.w] - bl);
      if (val)
        reinterpret_cast<ushort4*>(E + ((size_t)((b << 11) + t)) * Vv)[lane] = o;
      if ((lane == 0) & val) {
        lse_local += __logf(s[j]);
        Ebs[(b << 11) + ((t == 0) ? 2047 : t - 1)] = v[j].x;   // row[0] = blank
      }
    }
  }
  if (lane == 0) wpart[w] = lse_local;
  __syncthreads();
  if (threadIdx.x == 0)
    gpart[blockIdx.x] = wpart[0] + wpart[1] + wpart[2] + wpart[3];
}

// ---------------------------------------------------------------------------
// Kernel B: bidirectional max-plus Viterbi, 2 waves per batch (R7 structure,
// potential-shifted). Blank states: pure max. Labels: max3 + e~.
//   wave0: alpha~ forward t=0..M (em-inclusive), M=(L-2)>>1
//   wave1: beta~ backward t=L-1..M+1  (state 512 invariant!)
//   merge: vpart[b] = max_s(...) + Sum(blank[0..L-1])
// ---------------------------------------------------------------------------
#define PG 8
__global__ __launch_bounds__(128) void viterbi_kernel(
    const unsigned short* __restrict__ E, const float* __restrict__ Ebs,
    const int* __restrict__ targets, const int* __restrict__ llen,
    const int* __restrict__ tlen, float* __restrict__ vpart) {
  __shared__ __align__(16) float LB[2048];   // blanks (shifted layout), 8 KB
  __shared__ float Bt[520];
  const int b = blockIdx.x;
  const int lane = threadIdx.x & 63;
  const int wv = threadIdx.x >> 6;
  const int L = llen[b];
  const int tl = tlen[b];
  const int M = (L - 2) >> 1;
  const int4 lb = reinterpret_cast<const int4*>(targets + (b << 8))[lane];
  const uint2* __restrict__ Erow = reinterpret_cast<const uint2*>(E) + ((size_t)(b << 11) << 6);
  const float* __restrict__ Ebb = Ebs + (b << 11);

  // cooperative blank preload: 2048 floats (used only for init + compensation)
  {
    const float4* src = reinterpret_cast<const float4*>(Ebb);
    float4* dst = reinterpret_cast<float4*>(LB);
    for (int i = threadIdx.x; i < 512; i += 128) dst[i] = src[i];
  }
  __syncthreads();

  float a0 = NEGF, a1 = NEGF, a2 = NEGF, a3 = NEGF, a4 = NEGF,
        a5 = NEGF, a6 = NEGF, a7 = NEGF, a8 = NEGF;

  if (wv == 0) {
    // ---------------- forward wave (shifted alpha) ----------------
    const int prevw = __shfl_up(lb.w, 1);
    const bool sk0 = (lane != 0) && (lb.x != prevw);
    const bool sk1 = (lb.y != lb.x);
    const bool sk2 = (lb.z != lb.y);
    const bool sk3 = (lb.w != lb.z);
    if (lane == 0) {
      a0 = 0.f;                                                 // blank[0] - C(0)
      a1 = bf2f_lo((uint32)*reinterpret_cast<const unsigned short*>(E + ((size_t)(b << 11) << 8)));
    }
    uint2 pf[PG][4];
    auto fetchf = [&](int slot, int k) {
      const int kk = (k > 511) ? 511 : k;
#pragma unroll
      for (int j = 0; j < 4; ++j) {
        int r = 1 + 4 * kk + j; r = (r > 2047) ? 2047 : r;
        pf[slot][j] = Erow[(size_t)(r << 6) + lane];
      }
    };
    auto stepf = [&](uint2 em) {
      const float e0 = bf2f_lo(em.x), e1 = bf2f_hi(em.x);
      const float e2 = bf2f_lo(em.y), e3 = bf2f_hi(em.y);
      const float am1 = dpp_shr1(NEGF, a7);                     // lane0 -> NEGF
      const float x0 = fmaxf(a0, am1);
      const float x1 = fmaxf(fmaxf(a1, a0), sk0 ? am1 : NEGF) + e0;
      const float x2 = fmaxf(a2, a1);
      const float x3 = fmaxf(fmaxf(a3, a2), sk1 ? a1 : NEGF) + e1;
      const float x4 = fmaxf(a4, a3);
      const float x5 = fmaxf(fmaxf(a5, a4), sk2 ? a3 : NEGF) + e2;
      const float x6 = fmaxf(a6, a5);
      const float x7 = fmaxf(fmaxf(a7, a6), sk3 ? a5 : NEGF) + e3;
      const float x8 = fmaxf(a8, a7);
      a0 = x0; a1 = x1; a2 = x2; a3 = x3; a4 = x4; a5 = x5; a6 = x6; a7 = x7; a8 = x8;
    };
    const int n = M, Gf = n >> 2, remf = n & 3;
#pragma unroll
    for (int s = 0; s < PG; ++s) fetchf(s, s);
    __builtin_amdgcn_sched_barrier(0);
    int g = 0;
    while (g + PG <= Gf) {
#pragma unroll
      for (int s = 0; s < PG; ++s) {
#pragma unroll
        for (int j = 0; j < 4; ++j) stepf(pf[s][j]);
        fetchf(s, g + s + PG);
        __builtin_amdgcn_sched_barrier(0);
      }
      g += PG;
    }
    const int left = Gf - g;   // 0..PG-1
#pragma unroll
    for (int s = 0; s < PG; ++s) {
      if (s < left) {
#pragma unroll
        for (int j = 0; j < 4; ++j) stepf(pf[s][j]);
      }
    }
#pragma unroll
    for (int s = 0; s < PG; ++s) {
      if (s == left) {
#pragma unroll
        for (int j = 0; j < 4; ++j)
          if (j < remf) stepf(pf[s][j]);
      }
    }
  } else {
    // ---------------- backward wave (shifted beta) ----------------
    const int nlabx = __shfl_down(lb.x, 1);
    const bool kb0 = (lb.y != lb.x);
    const bool kb1 = (lb.z != lb.y);
    const bool kb2 = (lb.w != lb.z);
    const bool kb3 = (lane < 63) && (nlabx != lb.w);
    {
      const uint2 er = Erow[(size_t)((L - 1) << 6) + lane];
      const float e0 = bf2f_lo(er.x), e1 = bf2f_hi(er.x);
      const float e2 = bf2f_lo(er.y), e3 = bf2f_hi(er.y);
      const int s0 = 8 * lane, tb = 2 * tl, tm = 2 * tl - 1;
      a0 = (s0     == tb) ? 0.f : NEGF;
      a1 = (s0 + 1 == tm) ? e0  : NEGF;
      a2 = (s0 + 2 == tb) ? 0.f : NEGF;
      a3 = (s0 + 3 == tm) ? e1  : NEGF;
      a4 = (s0 + 4 == tb) ? 0.f : NEGF;
      a5 = (s0 + 5 == tm) ? e2  : NEGF;
      a6 = (s0 + 6 == tb) ? 0.f : NEGF;
      a7 = (s0 + 7 == tm) ? e3  : NEGF;
      a8 = ((lane == 63) && (tb == 512)) ? 0.f : NEGF;
    }
    uint2 qf[PG][4];
    auto fetchb = [&](int slot, int k) {
#pragma unroll
      for (int j = 0; j < 4; ++j) {
        int r = L - 2 - 4 * k - j; r = (r < 1) ? 1 : r;
        qf[slot][j] = Erow[(size_t)(r << 6) + lane];
      }
    };
    auto stepb = [&](uint2 em) {
      const float e0 = bf2f_lo(em.x), e1 = bf2f_hi(em.x);
      const float e2 = bf2f_lo(em.y), e3 = bf2f_hi(em.y);
      const float bn0 = dpp_shl1(a8, a0);     // lane l: a0[l+1]; lane63: own a8
      const float bn1 = dpp_shl1(NEGF, a1);   // lane l: a1[l+1]; lane63: NEGF
      const float y0 = fmaxf(a0, a1);
      const float y1 = fmaxf(fmaxf(a1, a2), kb0 ? a3 : NEGF) + e0;
      const float y2 = fmaxf(a2, a3);
      const float y3 = fmaxf(fmaxf(a3, a4), kb1 ? a5 : NEGF) + e1;
      const float y4 = fmaxf(a4, a5);
      const float y5 = fmaxf(fmaxf(a5, a6), kb2 ? a7 : NEGF) + e2;
      const float y6 = fmaxf(a6, a7);
      const float y7 = fmaxf(fmaxf(a7, bn0), kb3 ? bn1 : NEGF) + e3;
      // y8 = a8 (state 512 is invariant under the shift)
      a0 = y0; a1 = y1; a2 = y2; a3 = y3; a4 = y4; a5 = y5; a6 = y6; a7 = y7;
    };
    const int n = L - 2 - M, Gb = n >> 2, remb = n & 3;
#pragma unroll
    for (int s = 0; s < PG; ++s) fetchb(s, s);
    __builtin_amdgcn_sched_barrier(0);
    int g = 0;
    while (g + PG <= Gb) {
#pragma unroll
      for (int s = 0; s < PG; ++s) {
#pragma unroll
        for (int j = 0; j < 4; ++j) stepb(qf[s][j]);
        fetchb(s, g + s + PG);
        __builtin_amdgcn_sched_barrier(0);
      }
      g += PG;
    }
    const int left = Gb - g;
#pragma unroll
    for (int s = 0; s < PG; ++s) {
      if (s < left) {
#pragma unroll
        for (int j = 0; j < 4; ++j) stepb(qf[s][j]);
      }
    }
#pragma unroll
    for (int s = 0; s < PG; ++s) {
      if (s == left) {
#pragma unroll
        for (int j = 0; j < 4; ++j)
          if (j < remb) stepb(qf[s][j]);
      }
    }
    // dump beta~[M+1] to LDS (+NEG padding)
    Bt[8 * lane + 0] = a0; Bt[8 * lane + 1] = a1;
    Bt[8 * lane + 2] = a2; Bt[8 * lane + 3] = a3;
    Bt[8 * lane + 4] = a4; Bt[8 * lane + 5] = a5;
    Bt[8 * lane + 6] = a6; Bt[8 * lane + 7] = a7;
    if (lane == 63) Bt[512] = a8;
    if (lane == 0) { Bt[513] = NEGF; Bt[514] = NEGF; }
  }
  __syncthreads();
  if (wv == 0) {
    const int nlabx = __shfl_down(lb.x, 1);
    const bool kb0 = (lb.y != lb.x);
    const bool kb1 = (lb.z != lb.y);
    const bool kb2 = (lb.w != lb.z);
    const bool kb3 = (lane < 63) && (nlabx != lb.w);
    const int s0 = 8 * lane;
    float best;
    best =             a0 + fmaxf(Bt[s0],     Bt[s0 + 1]);
    best = fmaxf(best, a1 + fmaxf(fmaxf(Bt[s0 + 1], Bt[s0 + 2]), kb0 ? Bt[s0 + 3] : NEGF));
    best = fmaxf(best, a2 + fmaxf(Bt[s0 + 2], Bt[s0 + 3]));
    best = fmaxf(best, a3 + fmaxf(fmaxf(Bt[s0 + 3], Bt[s0 + 4]), kb1 ? Bt[s0 + 5] : NEGF));
    best = fmaxf(best, a4 + fmaxf(Bt[s0 + 4], Bt[s0 + 5]));
    best = fmaxf(best, a5 + fmaxf(fmaxf(Bt[s0 + 5], Bt[s0 + 6]), kb2 ? Bt[s0 + 7] : NEGF));
    best = fmaxf(best, a6 + fmaxf(Bt[s0 + 6], Bt[s0 + 7]));
    best = fmaxf(best, a7 + fmaxf(fmaxf(Bt[s0 + 7], Bt[s0 + 8]), kb3 ? Bt[s0 + 9] : NEGF));
    best = fmaxf(best, a8 + Bt[512]);
    // compensation: C = Sum_{t=0..L-1} blank[t] = LB[2047] + Sum_{i<=L-2} LB[i]
    float csum = 0.f;
#pragma unroll
    for (int i = 0; i < 32; ++i) {
      const int idx = lane + (i << 6);
      csum += (idx <= L - 2) ? LB[idx] : 0.f;
    }
#pragma unroll
    for (int off = 32; off; off >>= 1) {
      best = fmaxf(best, __shfl_down(best, off));
      csum += __shfl_down(csum, off);
    }
    if (lane == 0) vpart[b] = best + csum + LB[2047];
  }
}

// ---------------------------------------------------------------------------
// Kernel C: out = (sum(gpart) - sum(vpart)) / sum(L_b)
// ---------------------------------------------------------------------------
__global__ __launch_bounds__(256) void finalize_kernel(
    const int* __restrict__ llen, const float* __restrict__ gpart,
    const float* __restrict__ vpart, float* __restrict__ out) {
  __shared__ float sred[4], lred[4];
  const int t = threadIdx.x, lane = t & 63, w = t >> 6;
  float s = 0.f;
#pragma unroll
  for (int i = 0; i < 8; ++i) s += gpart[t + (i << 8)];
  float lf = 0.f;
  if (t < 64) { s -= vpart[t]; lf = (float)llen[t]; }
#pragma unroll
  for (int off = 32; off; off >>= 1) {
    s += __shfl_down(s, off);
    lf += __shfl_down(lf, off);
  }
  if (lane == 0) { sred[w] = s; lred[w] = lf; }
  __syncthreads();
  if (t == 0)
    out[0] = (sred[0] + sred[1] + sred[2] + sred[3]) /
             (lred[0] + lred[1] + lred[2] + lred[3]);
}

extern "C" void kernel_launch(void* const* d_in, const int* in_sizes, int n_in,
                              void* d_out, int out_size, void* d_ws, size_t ws_size,
                              hipStream_t stream) {
  const float* logits  = (const float*)d_in[0];   // [B,T,V] fp32
  const int*   targets = (const int*)d_in[1];     // [B,U] int32
  const int*   llen    = (const int*)d_in[2];     // [B]
  const int*   tlen    = (const int*)d_in[3];     // [B]
  float* out = (float*)d_out;

  // ws layout: [0,8K) gpart[2048] | [8K,8K+256) vpart[64] |
  //            [16384, +512K) Ebs fp32 | [1MiB, +64MiB) E bf16
  float*          gpart = (float*)d_ws;
  float*          vpart = (float*)d_ws + 2048;
  float*          Ebs   = (float*)((char*)d_ws + 16384);
  unsigned short* E     = (unsigned short*)((char*)d_ws + (1u << 20));

  gather_lse_kernel<<<Bb * 32, 256, 0, stream>>>(logits, targets, llen, gpart, Ebs, E);
  viterbi_kernel<<<Bb, 128, 0, stream>>>(E, Ebs, targets, llen, tlen, vpart);
  finalize_kernel<<<1, 256, 0, stream>>>(llen, gpart, vpart, out);
}

// Round 6
// 251.657 us; speedup vs baseline: 1.3517x; 1.0348x over previous
//
#include <hip/hip_runtime.h>

#define NEGF -1e30f
typedef unsigned int uint32;

static constexpr int Bb = 64, Tt = 2048, Vv = 256, Uu = 256;
// S = 2*U+1 = 513 states; lane l owns states 8l..8l+7 (+512 on lane 63).
// R13: quad-grouped fp16 emission layout + v_fma_mix fused unpack+add.
//   E2[b][q][lane][j][4 labels fp16], q = t>>2, j = t&3  (2048 B per quad,
//   per-batch region 512 quads = 1 MiB; same 64 MiB total as before).
//   Viterbi fetch group = 2 x dwordx4 + one pointer bump (no clamps: all
//   prefetch over/under-runs stay inside the batch's 1 MiB region).
//   E stores fp16(logit[label]-logit[blank]) (potential shift from R12);
//   the label-state add is one v_fma_mix_f32 (op_sel picks the half).
// Cadence model (R7/R8/R12 fits): time = slots/step x ~4.85 cyc. This cuts
// ~31 -> ~20 slots/step.

__device__ __forceinline__ unsigned short f2h(float f) {
  return __builtin_bit_cast(unsigned short, (_Float16)f);
}
__device__ __forceinline__ float fp16lo(uint32 w) {
  return (float)__builtin_bit_cast(_Float16, (unsigned short)(w & 0xffffu));
}
__device__ __forceinline__ float fp16hi(uint32 w) {
  return (float)__builtin_bit_cast(_Float16, (unsigned short)(w >> 16));
}
// acc + f32(fp16 half of w): one VOP3P op.
__device__ __forceinline__ float addmix_lo(float acc, uint32 w) {
  float d;
  asm("v_fma_mix_f32 %0, %1, 1.0, %2 op_sel:[0,0,0] op_sel_hi:[1,0,0]"
      : "=v"(d) : "v"(w), "v"(acc));
  return d;
}
__device__ __forceinline__ float addmix_hi(float acc, uint32 w) {
  float d;
  asm("v_fma_mix_f32 %0, %1, 1.0, %2 op_sel:[1,0,0] op_sel_hi:[1,0,0]"
      : "=v"(d) : "v"(w), "v"(acc));
  return d;
}

// DPP wave shifts: shr1: lane l <- l-1 (lane0 keeps old); shl1: lane l <- l+1 (lane63 keeps old).
__device__ __forceinline__ float dpp_shr1(float old, float src) {
  return __builtin_bit_cast(float, __builtin_amdgcn_update_dpp(
      __builtin_bit_cast(int, old), __builtin_bit_cast(int, src), 0x138, 0xF, 0xF, false));
}
__device__ __forceinline__ float dpp_shl1(float old, float src) {
  return __builtin_bit_cast(float, __builtin_amdgcn_update_dpp(
      __builtin_bit_cast(int, old), __builtin_bit_cast(int, src), 0x130, 0xF, 0xF, false));
}

// ---------------------------------------------------------------------------
// Kernel A: one streaming pass over logits; wave w handles 8 CONSECUTIVE rows
// tbase..tbase+7 (quad-friendly for the E2 layout).
//   - gpart[block] = partial sum of logsumexp over valid frames
//   - E2 quad layout, fp16(label - blank)
//   - Ebs shifted-blank array (raw f32 blanks for compensation)
// ---------------------------------------------------------------------------
__global__ __launch_bounds__(256) void gather_lse_kernel(
    const float* __restrict__ logits, const int* __restrict__ targets,
    const int* __restrict__ llen, float* __restrict__ gpart,
    float* __restrict__ Ebs, unsigned short* __restrict__ E) {
  __shared__ __align__(16) float buf[4][8][Vv];   // 32 KB
  __shared__ float wpart[4];
  const int b = blockIdx.x >> 5;
  const int c = blockIdx.x & 31;
  const int w = threadIdx.x >> 6;
  const int lane = threadIdx.x & 63;
  const int L = llen[b];
  const int4 lb = reinterpret_cast<const int4*>(targets + (b << 8))[lane];
  const float* __restrict__ lgb = logits + (size_t)b * (Tt * Vv);
  unsigned short* __restrict__ Eb2 = E + ((size_t)b << 19);   // 2^19 ushorts = 1 MiB
  float lse_local = 0.f;
#pragma unroll
  for (int k = 0; k < 2; ++k) {
    const int tbase = (c << 6) + (k << 5) + (w << 3);   // rows tbase..tbase+7
    if (tbase >= L) break;                              // wave-uniform
    float4 v[8];
#pragma unroll
    for (int j = 0; j < 8; ++j)
      v[j] = reinterpret_cast<const float4*>(lgb + (size_t)(tbase + j) * Vv)[lane];
    float s[8];
#pragma unroll
    for (int j = 0; j < 8; ++j)
      s[j] = __expf(v[j].x) + __expf(v[j].y) + __expf(v[j].z) + __expf(v[j].w);
#pragma unroll
    for (int off = 32; off; off >>= 1) {
#pragma unroll
      for (int j = 0; j < 8; ++j) s[j] += __shfl_down(s[j], off);
    }
#pragma unroll
    for (int j = 0; j < 8; ++j)
      reinterpret_cast<float4*>(&buf[w][j][0])[lane] = v[j];
#pragma unroll
    for (int j = 0; j < 8; ++j) {                 // intra-wave DS ordering
      const int t = tbase + j;
      const bool val = t < L;
      const float bl = buf[w][j][0];              // blank of this row (broadcast)
      ushort4 o;
      o.x = f2h(buf[w][j][lb.x] - bl); o.y = f2h(buf[w][j][lb.y] - bl);
      o.z = f2h(buf[w][j][lb.z] - bl); o.w = f2h(buf[w][j][lb.w] - bl);
      if (val)
        *reinterpret_cast<ushort4*>(Eb2 + (size_t)(t >> 2) * 1024 + (lane << 4) + ((t & 3) << 2)) = o;
      if ((lane == 0) & val) {
        lse_local += __logf(s[j]);
        Ebs[(b << 11) + ((t == 0) ? 2047 : t - 1)] = v[j].x;   // row[0] = blank
      }
    }
  }
  if (lane == 0) wpart[w] = lse_local;
  __syncthreads();
  if (threadIdx.x == 0)
    gpart[blockIdx.x] = wpart[0] + wpart[1] + wpart[2] + wpart[3];
}

// ---------------------------------------------------------------------------
// Kernel B: bidirectional max-plus Viterbi, 2 waves per batch, potential-
// shifted, quad-grouped fp16 fetch.
// ---------------------------------------------------------------------------
#define PG 8
__global__ __launch_bounds__(128) void viterbi_kernel(
    const unsigned short* __restrict__ E, const float* __restrict__ Ebs,
    const int* __restrict__ targets, const int* __restrict__ llen,
    const int* __restrict__ tlen, float* __restrict__ vpart) {
  __shared__ __align__(16) float LB[2048];   // blanks (shifted layout), 8 KB
  __shared__ float Bt[520];
  const int b = blockIdx.x;
  const int lane = threadIdx.x & 63;
  const int wv = threadIdx.x >> 6;
  const int L = llen[b];
  const int tl = tlen[b];
  const int M = (L - 2) >> 1;
  const int4 lb = reinterpret_cast<const int4*>(targets + (b << 8))[lane];
  const unsigned short* __restrict__ Eb2 = E + ((size_t)b << 19);
  const float* __restrict__ Ebb = Ebs + (b << 11);
  // row r (4 fp16 labels for this lane) in the quad layout:
  auto ldrow = [&](int r) {
    return *reinterpret_cast<const uint2*>(Eb2 + (size_t)(r >> 2) * 1024 + (lane << 4) + ((r & 3) << 2));
  };

  // cooperative blank preload (merge-time compensation only)
  {
    const float4* src = reinterpret_cast<const float4*>(Ebb);
    float4* dst = reinterpret_cast<float4*>(LB);
    for (int i = threadIdx.x; i < 512; i += 128) dst[i] = src[i];
  }
  __syncthreads();

  float a0 = NEGF, a1 = NEGF, a2 = NEGF, a3 = NEGF, a4 = NEGF,
        a5 = NEGF, a6 = NEGF, a7 = NEGF, a8 = NEGF;

  if (wv == 0) {
    // ---------------- forward wave (shifted alpha) ----------------
    const int prevw = __shfl_up(lb.w, 1);
    const bool sk0 = (lane != 0) && (lb.x != prevw);
    const bool sk1 = (lb.y != lb.x);
    const bool sk2 = (lb.z != lb.y);
    const bool sk3 = (lb.w != lb.z);
    if (lane == 0) {
      a0 = 0.f;
      a1 = fp16lo((uint32)Eb2[0]);     // label0 at t=0
    }
    auto stepf = [&](uint32 wx, uint32 wy) {
      const float am1 = dpp_shr1(NEGF, a7);                     // lane0 -> NEGF
      const float x0 = fmaxf(a0, am1);
      const float x1 = addmix_lo(fmaxf(fmaxf(a1, a0), sk0 ? am1 : NEGF), wx);
      const float x2 = fmaxf(a2, a1);
      const float x3 = addmix_hi(fmaxf(fmaxf(a3, a2), sk1 ? a1 : NEGF), wx);
      const float x4 = fmaxf(a4, a3);
      const float x5 = addmix_lo(fmaxf(fmaxf(a5, a4), sk2 ? a3 : NEGF), wy);
      const float x6 = fmaxf(a6, a5);
      const float x7 = addmix_hi(fmaxf(fmaxf(a7, a6), sk3 ? a5 : NEGF), wy);
      const float x8 = fmaxf(a8, a7);
      a0 = x0; a1 = x1; a2 = x2; a3 = x3; a4 = x4; a5 = x5; a6 = x6; a7 = x7; a8 = x8;
    };
    // ring over aligned quads 1.. (rows 4..M), peel rows 1..3 first
    uint4 pf[PG][2];
    const uint4* pq = reinterpret_cast<const uint4*>(Eb2 + 1024) + (lane << 1);
    auto fetchf = [&](int slot) { pf[slot][0] = pq[0]; pf[slot][1] = pq[1]; pq += 128; };
#pragma unroll
    for (int s = 0; s < PG; ++s) fetchf(s);
    {   // peel rows 1,2,3 (M >= 511 always)
      const uint2 w1 = ldrow(1), w2 = ldrow(2), w3 = ldrow(3);
      stepf(w1.x, w1.y); stepf(w2.x, w2.y); stepf(w3.x, w3.y);
    }
    __builtin_amdgcn_sched_barrier(0);
    const int n = M - 3, Gf = n >> 2, remf = n & 3;
    int g = 0;
    while (g + PG <= Gf) {
#pragma unroll
      for (int s = 0; s < PG; ++s) {
        stepf(pf[s][0].x, pf[s][0].y);
        stepf(pf[s][0].z, pf[s][0].w);
        stepf(pf[s][1].x, pf[s][1].y);
        stepf(pf[s][1].z, pf[s][1].w);
        fetchf(s);
        __builtin_amdgcn_sched_barrier(0);
      }
      g += PG;
    }
    const int left = Gf - g;   // 0..PG-1
#pragma unroll
    for (int s = 0; s < PG; ++s) {
      if (s < left) {
        stepf(pf[s][0].x, pf[s][0].y);
        stepf(pf[s][0].z, pf[s][0].w);
        stepf(pf[s][1].x, pf[s][1].y);
        stepf(pf[s][1].z, pf[s][1].w);
      }
    }
#pragma unroll
    for (int s = 0; s < PG; ++s) {
      if (s == left) {
        if (remf > 0) stepf(pf[s][0].x, pf[s][0].y);
        if (remf > 1) stepf(pf[s][0].z, pf[s][0].w);
        if (remf > 2) stepf(pf[s][1].x, pf[s][1].y);
      }
    }
  } else {
    // ---------------- backward wave (shifted beta) ----------------
    const int nlabx = __shfl_down(lb.x, 1);
    const bool kb0 = (lb.y != lb.x);
    const bool kb1 = (lb.z != lb.y);
    const bool kb2 = (lb.w != lb.z);
    const bool kb3 = (lane < 63) && (nlabx != lb.w);
    {
      const uint2 er = ldrow(L - 1);
      const float e0 = fp16lo(er.x), e1 = fp16hi(er.x);
      const float e2 = fp16lo(er.y), e3 = fp16hi(er.y);
      const int s0 = 8 * lane, tb = 2 * tl, tm = 2 * tl - 1;
      a0 = (s0     == tb) ? 0.f : NEGF;
      a1 = (s0 + 1 == tm) ? e0  : NEGF;
      a2 = (s0 + 2 == tb) ? 0.f : NEGF;
      a3 = (s0 + 3 == tm) ? e1  : NEGF;
      a4 = (s0 + 4 == tb) ? 0.f : NEGF;
      a5 = (s0 + 5 == tm) ? e2  : NEGF;
      a6 = (s0 + 6 == tb) ? 0.f : NEGF;
      a7 = (s0 + 7 == tm) ? e3  : NEGF;
      a8 = ((lane == 63) && (tb == 512)) ? 0.f : NEGF;
    }
    auto stepb = [&](uint32 wx, uint32 wy) {
      const float bn0 = dpp_shl1(a8, a0);     // lane l: a0[l+1]; lane63: own a8
      const float bn1 = dpp_shl1(NEGF, a1);   // lane l: a1[l+1]; lane63: NEGF
      const float y0 = fmaxf(a0, a1);
      const float y1 = addmix_lo(fmaxf(fmaxf(a1, a2), kb0 ? a3 : NEGF), wx);
      const float y2 = fmaxf(a2, a3);
      const float y3 = addmix_hi(fmaxf(fmaxf(a3, a4), kb1 ? a5 : NEGF), wx);
      const float y4 = fmaxf(a4, a5);
      const float y5 = addmix_lo(fmaxf(fmaxf(a5, a6), kb2 ? a7 : NEGF), wy);
      const float y6 = fmaxf(a6, a7);
      const float y7 = addmix_hi(fmaxf(fmaxf(a7, bn0), kb3 ? bn1 : NEGF), wy);
      // a8 invariant under the potential shift
      a0 = y0; a1 = y1; a2 = y2; a3 = y3; a4 = y4; a5 = y5; a6 = y6; a7 = y7;
    };
    const int e = L - 2;
    const int p = (e + 1) & 3;     // peel to make next row = 3 (mod 4)
    // ring over aligned quads descending from q0; prologue fetch overlaps peel
    uint4 qf[PG][2];
    const int q0 = (e - p) >> 2;
    const uint4* pq = reinterpret_cast<const uint4*>(Eb2) + ((size_t)q0 << 7) + (lane << 1);
    auto fetchb = [&](int slot) { qf[slot][0] = pq[0]; qf[slot][1] = pq[1]; pq -= 128; };
#pragma unroll
    for (int s = 0; s < PG; ++s) fetchb(s);
    {   // peel rows e, e-1, e-2 as needed (p wave-uniform, 0..3)
      uint2 pw0, pw1, pw2;
      if (p > 0) pw0 = ldrow(e);
      if (p > 1) pw1 = ldrow(e - 1);
      if (p > 2) pw2 = ldrow(e - 2);
      if (p > 0) stepb(pw0.x, pw0.y);
      if (p > 1) stepb(pw1.x, pw1.y);
      if (p > 2) stepb(pw2.x, pw2.y);
    }
    __builtin_amdgcn_sched_barrier(0);
    const int n = (e - M) - p, Gb = n >> 2, remb = n & 3;
    int g = 0;
    while (g + PG <= Gb) {
#pragma unroll
      for (int s = 0; s < PG; ++s) {
        stepb(qf[s][1].z, qf[s][1].w);
        stepb(qf[s][1].x, qf[s][1].y);
        stepb(qf[s][0].z, qf[s][0].w);
        stepb(qf[s][0].x, qf[s][0].y);
        fetchb(s);
        __builtin_amdgcn_sched_barrier(0);
      }
      g += PG;
    }
    const int left = Gb - g;
#pragma unroll
    for (int s = 0; s < PG; ++s) {
      if (s < left) {
        stepb(qf[s][1].z, qf[s][1].w);
        stepb(qf[s][1].x, qf[s][1].y);
        stepb(qf[s][0].z, qf[s][0].w);
        stepb(qf[s][0].x, qf[s][0].y);
      }
    }
#pragma unroll
    for (int s = 0; s < PG; ++s) {
      if (s == left) {
        if (remb > 0) stepb(qf[s][1].z, qf[s][1].w);
        if (remb > 1) stepb(qf[s][1].x, qf[s][1].y);
        if (remb > 2) stepb(qf[s][0].z, qf[s][0].w);
      }
    }
    // dump beta~[M+1] to LDS (+NEG padding)
    Bt[8 * lane + 0] = a0; Bt[8 * lane + 1] = a1;
    Bt[8 * lane + 2] = a2; Bt[8 * lane + 3] = a3;
    Bt[8 * lane + 4] = a4; Bt[8 * lane + 5] = a5;
    Bt[8 * lane + 6] = a6; Bt[8 * lane + 7] = a7;
    if (lane == 63) Bt[512] = a8;
    if (lane == 0) { Bt[513] = NEGF; Bt[514] = NEGF; }
  }
  __syncthreads();
  if (wv == 0) {
    const int nlabx = __shfl_down(lb.x, 1);
    const bool kb0 = (lb.y != lb.x);
    const bool kb1 = (lb.z != lb.y);
    const bool kb2 = (lb.w != lb.z);
    const bool kb3 = (lane < 63) && (nlabx != lb.w);
    const int s0 = 8 * lane;
    float best;
    best =             a0 + fmaxf(Bt[s0],     Bt[s0 + 1]);
    best = fmaxf(best, a1 + fmaxf(fmaxf(Bt[s0 + 1], Bt[s0 + 2]), kb0 ? Bt[s0 + 3] : NEGF));
    best = fmaxf(best, a2 + fmaxf(Bt[s0 + 2], Bt[s0 + 3]));
    best = fmaxf(best, a3 + fmaxf(fmaxf(Bt[s0 + 3], Bt[s0 + 4]), kb1 ? Bt[s0 + 5] : NEGF));
    best = fmaxf(best, a4 + fmaxf(Bt[s0 + 4], Bt[s0 + 5]));
    best = fmaxf(best, a5 + fmaxf(fmaxf(Bt[s0 + 5], Bt[s0 + 6]), kb2 ? Bt[s0 + 7] : NEGF));
    best = fmaxf(best, a6 + fmaxf(Bt[s0 + 6], Bt[s0 + 7]));
    best = fmaxf(best, a7 + fmaxf(fmaxf(Bt[s0 + 7], Bt[s0 + 8]), kb3 ? Bt[s0 + 9] : NEGF));
    best = fmaxf(best, a8 + Bt[512]);
    // compensation: C = Sum_{t=0..L-1} blank[t] = LB[2047] + Sum_{i<=L-2} LB[i]
    float csum = 0.f;
#pragma unroll
    for (int i = 0; i < 32; ++i) {
      const int idx = lane + (i << 6);
      csum += (idx <= L - 2) ? LB[idx] : 0.f;
    }
#pragma unroll
    for (int off = 32; off; off >>= 1) {
      best = fmaxf(best, __shfl_down(best, off));
      csum += __shfl_down(csum, off);
    }
    if (lane == 0) vpart[b] = best + csum + LB[2047];
  }
}

// ---------------------------------------------------------------------------
// Kernel C: out = (sum(gpart) - sum(vpart)) / sum(L_b)
// ---------------------------------------------------------------------------
__global__ __launch_bounds__(256) void finalize_kernel(
    const int* __restrict__ llen, const float* __restrict__ gpart,
    const float* __restrict__ vpart, float* __restrict__ out) {
  __shared__ float sred[4], lred[4];
  const int t = threadIdx.x, lane = t & 63, w = t >> 6;
  float s = 0.f;
#pragma unroll
  for (int i = 0; i < 8; ++i) s += gpart[t + (i << 8)];
  float lf = 0.f;
  if (t < 64) { s -= vpart[t]; lf = (float)llen[t]; }
#pragma unroll
  for (int off = 32; off; off >>= 1) {
    s += __shfl_down(s, off);
    lf += __shfl_down(lf, off);
  }
  if (lane == 0) { sred[w] = s; lred[w] = lf; }
  __syncthreads();
  if (t == 0)
    out[0] = (sred[0] + sred[1] + sred[2] + sred[3]) /
             (lred[0] + lred[1] + lred[2] + lred[3]);
}

extern "C" void kernel_launch(void* const* d_in, const int* in_sizes, int n_in,
                              void* d_out, int out_size, void* d_ws, size_t ws_size,
                              hipStream_t stream) {
  const float* logits  = (const float*)d_in[0];   // [B,T,V] fp32
  const int*   targets = (const int*)d_in[1];     // [B,U] int32
  const int*   llen    = (const int*)d_in[2];     // [B]
  const int*   tlen    = (const int*)d_in[3];     // [B]
  float* out = (float*)d_out;

  // ws layout: [0,8K) gpart[2048] | [8K,8K+256) vpart[64] |
  //            [16384, +512K) Ebs fp32 | [1MiB, +64MiB) E2 fp16 quad layout
  float*          gpart = (float*)d_ws;
  float*          vpart = (float*)d_ws + 2048;
  float*          Ebs   = (float*)((char*)d_ws + 16384);
  unsigned short* E     = (unsigned short*)((char*)d_ws + (1u << 20));

  gather_lse_kernel<<<Bb * 32, 256, 0, stream>>>(logits, targets, llen, gpart, Ebs, E);
  viterbi_kernel<<<Bb, 128, 0, stream>>>(E, Ebs, targets, llen, tlen, vpart);
  finalize_kernel<<<1, 256, 0, stream>>>(llen, gpart, vpart, out);
}

// Round 7
// 248.484 us; speedup vs baseline: 1.3690x; 1.0128x over previous
//
#include <hip/hip_runtime.h>

#define NEGF -1e30f
typedef unsigned int uint32;

static constexpr int Bb = 64, Tt = 2048, Vv = 256, Uu = 256;
// S = 2*U+1 = 513 states; lane l owns states 8l..8l+7 (+512 on lane 63).
// R14 = R13 viterbi (byte-identical) + gather E-store density fix.
//   E2[b][q][lane][j][4 labels fp16], q = t>>2, j = t&3 (2 KB per quad).
//   R13 wrote one ushort4 (8 B) per row at 32 B stride (25% line density,
//   suspected HBM write amplification). R14 accumulates the quad's 4 rows in
//   registers and issues two dense dwordx4 stores per lane per quad.
// Cadence model (R7..R13 fits): viterbi time ~= slots/step x ~5-6.5 cyc.

__device__ __forceinline__ unsigned short f2h(float f) {
  return __builtin_bit_cast(unsigned short, (_Float16)f);
}
__device__ __forceinline__ uint32 pk2h_rne(float a, float b) {   // RNE both halves
  return (uint32)f2h(a) | ((uint32)f2h(b) << 16);
}
__device__ __forceinline__ float fp16lo(uint32 w) {
  return (float)__builtin_bit_cast(_Float16, (unsigned short)(w & 0xffffu));
}
__device__ __forceinline__ float fp16hi(uint32 w) {
  return (float)__builtin_bit_cast(_Float16, (unsigned short)(w >> 16));
}
// acc + f32(fp16 half of w): one VOP3P op.
__device__ __forceinline__ float addmix_lo(float acc, uint32 w) {
  float d;
  asm("v_fma_mix_f32 %0, %1, 1.0, %2 op_sel:[0,0,0] op_sel_hi:[1,0,0]"
      : "=v"(d) : "v"(w), "v"(acc));
  return d;
}
__device__ __forceinline__ float addmix_hi(float acc, uint32 w) {
  float d;
  asm("v_fma_mix_f32 %0, %1, 1.0, %2 op_sel:[1,0,0] op_sel_hi:[1,0,0]"
      : "=v"(d) : "v"(w), "v"(acc));
  return d;
}

// DPP wave shifts: shr1: lane l <- l-1 (lane0 keeps old); shl1: lane l <- l+1 (lane63 keeps old).
__device__ __forceinline__ float dpp_shr1(float old, float src) {
  return __builtin_bit_cast(float, __builtin_amdgcn_update_dpp(
      __builtin_bit_cast(int, old), __builtin_bit_cast(int, src), 0x138, 0xF, 0xF, false));
}
__device__ __forceinline__ float dpp_shl1(float old, float src) {
  return __builtin_bit_cast(float, __builtin_amdgcn_update_dpp(
      __builtin_bit_cast(int, old), __builtin_bit_cast(int, src), 0x130, 0xF, 0xF, false));
}

// ---------------------------------------------------------------------------
// Kernel A: one streaming pass over logits; wave w handles 8 CONSECUTIVE rows
// tbase..tbase+7 (= 2 aligned quads).
//   - gpart[block] = partial sum of logsumexp over valid frames
//   - E2 quad layout, fp16(label - blank), dense 16B stores
//   - Ebs shifted-blank array (raw f32 blanks for compensation)
// ---------------------------------------------------------------------------
__global__ __launch_bounds__(256) void gather_lse_kernel(
    const float* __restrict__ logits, const int* __restrict__ targets,
    const int* __restrict__ llen, float* __restrict__ gpart,
    float* __restrict__ Ebs, unsigned short* __restrict__ E) {
  __shared__ __align__(16) float buf[4][8][Vv];   // 32 KB
  __shared__ float wpart[4];
  const int b = blockIdx.x >> 5;
  const int c = blockIdx.x & 31;
  const int w = threadIdx.x >> 6;
  const int lane = threadIdx.x & 63;
  const int L = llen[b];
  const int4 lb = reinterpret_cast<const int4*>(targets + (b << 8))[lane];
  const float* __restrict__ lgb = logits + (size_t)b * (Tt * Vv);
  unsigned short* __restrict__ Eb2 = E + ((size_t)b << 19);   // 2^19 ushorts = 1 MiB
  float lse_local = 0.f;
#pragma unroll
  for (int k = 0; k < 2; ++k) {
    const int tbase = (c << 6) + (k << 5) + (w << 3);   // rows tbase..tbase+7
    if (tbase >= L) break;                              // wave-uniform
    float4 v[8];
#pragma unroll
    for (int j = 0; j < 8; ++j)
      v[j] = reinterpret_cast<const float4*>(lgb + (size_t)(tbase + j) * Vv)[lane];
    float s[8];
#pragma unroll
    for (int j = 0; j < 8; ++j)
      s[j] = __expf(v[j].x) + __expf(v[j].y) + __expf(v[j].z) + __expf(v[j].w);
#pragma unroll
    for (int off = 32; off; off >>= 1) {
#pragma unroll
      for (int j = 0; j < 8; ++j) s[j] += __shfl_down(s[j], off);
    }
#pragma unroll
    for (int j = 0; j < 8; ++j)
      reinterpret_cast<float4*>(&buf[w][j][0])[lane] = v[j];
    uint2 u4[4];
#pragma unroll
    for (int j = 0; j < 8; ++j) {                 // intra-wave DS ordering
      const int t = tbase + j;
      const float bl = buf[w][j][0];              // blank of this row (broadcast)
      u4[j & 3] = make_uint2(pk2h_rne(buf[w][j][lb.x] - bl, buf[w][j][lb.y] - bl),
                             pk2h_rne(buf[w][j][lb.z] - bl, buf[w][j][lb.w] - bl));
      if ((j & 3) == 3) {
        if (t - 3 < L) {                          // first row of quad valid
          unsigned short* qptr = Eb2 + (size_t)(t >> 2) * 1024 + (lane << 4);
          *reinterpret_cast<uint4*>(qptr)     = make_uint4(u4[0].x, u4[0].y, u4[1].x, u4[1].y);
          *reinterpret_cast<uint4*>(qptr + 8) = make_uint4(u4[2].x, u4[2].y, u4[3].x, u4[3].y);
        }
      }
      if ((lane == 0) & (t < L)) {
        lse_local += __logf(s[j]);
        Ebs[(b << 11) + ((t == 0) ? 2047 : t - 1)] = v[j].x;   // row[0] = blank
      }
    }
  }
  if (lane == 0) wpart[w] = lse_local;
  __syncthreads();
  if (threadIdx.x == 0)
    gpart[blockIdx.x] = wpart[0] + wpart[1] + wpart[2] + wpart[3];
}

// ---------------------------------------------------------------------------
// Kernel B: bidirectional max-plus Viterbi, 2 waves per batch, potential-
// shifted, quad-grouped fp16 fetch. (byte-identical to R13)
// ---------------------------------------------------------------------------
#define PG 8
__global__ __launch_bounds__(128) void viterbi_kernel(
    const unsigned short* __restrict__ E, const float* __restrict__ Ebs,
    const int* __restrict__ targets, const int* __restrict__ llen,
    const int* __restrict__ tlen, float* __restrict__ vpart) {
  __shared__ __align__(16) float LB[2048];   // blanks (shifted layout), 8 KB
  __shared__ float Bt[520];
  const int b = blockIdx.x;
  const int lane = threadIdx.x & 63;
  const int wv = threadIdx.x >> 6;
  const int L = llen[b];
  const int tl = tlen[b];
  const int M = (L - 2) >> 1;
  const int4 lb = reinterpret_cast<const int4*>(targets + (b << 8))[lane];
  const unsigned short* __restrict__ Eb2 = E + ((size_t)b << 19);
  const float* __restrict__ Ebb = Ebs + (b << 11);
  // row r (4 fp16 labels for this lane) in the quad layout:
  auto ldrow = [&](int r) {
    return *reinterpret_cast<const uint2*>(Eb2 + (size_t)(r >> 2) * 1024 + (lane << 4) + ((r & 3) << 2));
  };

  // cooperative blank preload (merge-time compensation only)
  {
    const float4* src = reinterpret_cast<const float4*>(Ebb);
    float4* dst = reinterpret_cast<float4*>(LB);
    for (int i = threadIdx.x; i < 512; i += 128) dst[i] = src[i];
  }
  __syncthreads();

  float a0 = NEGF, a1 = NEGF, a2 = NEGF, a3 = NEGF, a4 = NEGF,
        a5 = NEGF, a6 = NEGF, a7 = NEGF, a8 = NEGF;

  if (wv == 0) {
    // ---------------- forward wave (shifted alpha) ----------------
    const int prevw = __shfl_up(lb.w, 1);
    const bool sk0 = (lane != 0) && (lb.x != prevw);
    const bool sk1 = (lb.y != lb.x);
    const bool sk2 = (lb.z != lb.y);
    const bool sk3 = (lb.w != lb.z);
    if (lane == 0) {
      a0 = 0.f;
      a1 = fp16lo((uint32)Eb2[0]);     // label0 at t=0
    }
    auto stepf = [&](uint32 wx, uint32 wy) {
      const float am1 = dpp_shr1(NEGF, a7);                     // lane0 -> NEGF
      const float x0 = fmaxf(a0, am1);
      const float x1 = addmix_lo(fmaxf(fmaxf(a1, a0), sk0 ? am1 : NEGF), wx);
      const float x2 = fmaxf(a2, a1);
      const float x3 = addmix_hi(fmaxf(fmaxf(a3, a2), sk1 ? a1 : NEGF), wx);
      const float x4 = fmaxf(a4, a3);
      const float x5 = addmix_lo(fmaxf(fmaxf(a5, a4), sk2 ? a3 : NEGF), wy);
      const float x6 = fmaxf(a6, a5);
      const float x7 = addmix_hi(fmaxf(fmaxf(a7, a6), sk3 ? a5 : NEGF), wy);
      const float x8 = fmaxf(a8, a7);
      a0 = x0; a1 = x1; a2 = x2; a3 = x3; a4 = x4; a5 = x5; a6 = x6; a7 = x7; a8 = x8;
    };
    // ring over aligned quads 1.. (rows 4..M), peel rows 1..3 first
    uint4 pf[PG][2];
    const uint4* pq = reinterpret_cast<const uint4*>(Eb2 + 1024) + (lane << 1);
    auto fetchf = [&](int slot) { pf[slot][0] = pq[0]; pf[slot][1] = pq[1]; pq += 128; };
#pragma unroll
    for (int s = 0; s < PG; ++s) fetchf(s);
    {   // peel rows 1,2,3 (M >= 511 always)
      const uint2 w1 = ldrow(1), w2 = ldrow(2), w3 = ldrow(3);
      stepf(w1.x, w1.y); stepf(w2.x, w2.y); stepf(w3.x, w3.y);
    }
    __builtin_amdgcn_sched_barrier(0);
    const int n = M - 3, Gf = n >> 2, remf = n & 3;
    int g = 0;
    while (g + PG <= Gf) {
#pragma unroll
      for (int s = 0; s < PG; ++s) {
        stepf(pf[s][0].x, pf[s][0].y);
        stepf(pf[s][0].z, pf[s][0].w);
        stepf(pf[s][1].x, pf[s][1].y);
        stepf(pf[s][1].z, pf[s][1].w);
        fetchf(s);
        __builtin_amdgcn_sched_barrier(0);
      }
      g += PG;
    }
    const int left = Gf - g;   // 0..PG-1
#pragma unroll
    for (int s = 0; s < PG; ++s) {
      if (s < left) {
        stepf(pf[s][0].x, pf[s][0].y);
        stepf(pf[s][0].z, pf[s][0].w);
        stepf(pf[s][1].x, pf[s][1].y);
        stepf(pf[s][1].z, pf[s][1].w);
      }
    }
#pragma unroll
    for (int s = 0; s < PG; ++s) {
      if (s == left) {
        if (remf > 0) stepf(pf[s][0].x, pf[s][0].y);
        if (remf > 1) stepf(pf[s][0].z, pf[s][0].w);
        if (remf > 2) stepf(pf[s][1].x, pf[s][1].y);
      }
    }
  } else {
    // ---------------- backward wave (shifted beta) ----------------
    const int nlabx = __shfl_down(lb.x, 1);
    const bool kb0 = (lb.y != lb.x);
    const bool kb1 = (lb.z != lb.y);
    const bool kb2 = (lb.w != lb.z);
    const bool kb3 = (lane < 63) && (nlabx != lb.w);
    {
      const uint2 er = ldrow(L - 1);
      const float e0 = fp16lo(er.x), e1 = fp16hi(er.x);
      const float e2 = fp16lo(er.y), e3 = fp16hi(er.y);
      const int s0 = 8 * lane, tb = 2 * tl, tm = 2 * tl - 1;
      a0 = (s0     == tb) ? 0.f : NEGF;
      a1 = (s0 + 1 == tm) ? e0  : NEGF;
      a2 = (s0 + 2 == tb) ? 0.f : NEGF;
      a3 = (s0 + 3 == tm) ? e1  : NEGF;
      a4 = (s0 + 4 == tb) ? 0.f : NEGF;
      a5 = (s0 + 5 == tm) ? e2  : NEGF;
      a6 = (s0 + 6 == tb) ? 0.f : NEGF;
      a7 = (s0 + 7 == tm) ? e3  : NEGF;
      a8 = ((lane == 63) && (tb == 512)) ? 0.f : NEGF;
    }
    auto stepb = [&](uint32 wx, uint32 wy) {
      const float bn0 = dpp_shl1(a8, a0);     // lane l: a0[l+1]; lane63: own a8
      const float bn1 = dpp_shl1(NEGF, a1);   // lane l: a1[l+1]; lane63: NEGF
      const float y0 = fmaxf(a0, a1);
      const float y1 = addmix_lo(fmaxf(fmaxf(a1, a2), kb0 ? a3 : NEGF), wx);
      const float y2 = fmaxf(a2, a3);
      const float y3 = addmix_hi(fmaxf(fmaxf(a3, a4), kb1 ? a5 : NEGF), wx);
      const float y4 = fmaxf(a4, a5);
      const float y5 = addmix_lo(fmaxf(fmaxf(a5, a6), kb2 ? a7 : NEGF), wy);
      const float y6 = fmaxf(a6, a7);
      const float y7 = addmix_hi(fmaxf(fmaxf(a7, bn0), kb3 ? bn1 : NEGF), wy);
      // a8 invariant under the potential shift
      a0 = y0; a1 = y1; a2 = y2; a3 = y3; a4 = y4; a5 = y5; a6 = y6; a7 = y7;
    };
    const int e = L - 2;
    const int p = (e + 1) & 3;     // peel to make next row = 3 (mod 4)
    // ring over aligned quads descending from q0; prologue fetch overlaps peel
    uint4 qf[PG][2];
    const int q0 = (e - p) >> 2;
    const uint4* pq = reinterpret_cast<const uint4*>(Eb2) + ((size_t)q0 << 7) + (lane << 1);
    auto fetchb = [&](int slot) { qf[slot][0] = pq[0]; qf[slot][1] = pq[1]; pq -= 128; };
#pragma unroll
    for (int s = 0; s < PG; ++s) fetchb(s);
    {   // peel rows e, e-1, e-2 as needed (p wave-uniform, 0..3)
      uint2 pw0, pw1, pw2;
      if (p > 0) pw0 = ldrow(e);
      if (p > 1) pw1 = ldrow(e - 1);
      if (p > 2) pw2 = ldrow(e - 2);
      if (p > 0) stepb(pw0.x, pw0.y);
      if (p > 1) stepb(pw1.x, pw1.y);
      if (p > 2) stepb(pw2.x, pw2.y);
    }
    __builtin_amdgcn_sched_barrier(0);
    const int n = (e - M) - p, Gb = n >> 2, remb = n & 3;
    int g = 0;
    while (g + PG <= Gb) {
#pragma unroll
      for (int s = 0; s < PG; ++s) {
        stepb(qf[s][1].z, qf[s][1].w);
        stepb(qf[s][1].x, qf[s][1].y);
        stepb(qf[s][0].z, qf[s][0].w);
        stepb(qf[s][0].x, qf[s][0].y);
        fetchb(s);
        __builtin_amdgcn_sched_barrier(0);
      }
      g += PG;
    }
    const int left = Gb - g;
#pragma unroll
    for (int s = 0; s < PG; ++s) {
      if (s < left) {
        stepb(qf[s][1].z, qf[s][1].w);
        stepb(qf[s][1].x, qf[s][1].y);
        stepb(qf[s][0].z, qf[s][0].w);
        stepb(qf[s][0].x, qf[s][0].y);
      }
    }
#pragma unroll
    for (int s = 0; s < PG; ++s) {
      if (s == left) {
        if (remb > 0) stepb(qf[s][1].z, qf[s][1].w);
        if (remb > 1) stepb(qf[s][1].x, qf[s][1].y);
        if (remb > 2) stepb(qf[s][0].z, qf[s][0].w);
      }
    }
    // dump beta~[M+1] to LDS (+NEG padding)
    Bt[8 * lane + 0] = a0; Bt[8 * lane + 1] = a1;
    Bt[8 * lane + 2] = a2; Bt[8 * lane + 3] = a3;
    Bt[8 * lane + 4] = a4; Bt[8 * lane + 5] = a5;
    Bt[8 * lane + 6] = a6; Bt[8 * lane + 7] = a7;
    if (lane == 63) Bt[512] = a8;
    if (lane == 0) { Bt[513] = NEGF; Bt[514] = NEGF; }
  }
  __syncthreads();
  if (wv == 0) {
    const int nlabx = __shfl_down(lb.x, 1);
    const bool kb0 = (lb.y != lb.x);
    const bool kb1 = (lb.z != lb.y);
    const bool kb2 = (lb.w != lb.z);
    const bool kb3 = (lane < 63) && (nlabx != lb.w);
    const int s0 = 8 * lane;
    float best;
    best =             a0 + fmaxf(Bt[s0],     Bt[s0 + 1]);
    best = fmaxf(best, a1 + fmaxf(fmaxf(Bt[s0 + 1], Bt[s0 + 2]), kb0 ? Bt[s0 + 3] : NEGF));
    best = fmaxf(best, a2 + fmaxf(Bt[s0 + 2], Bt[s0 + 3]));
    best = fmaxf(best, a3 + fmaxf(fmaxf(Bt[s0 + 3], Bt[s0 + 4]), kb1 ? Bt[s0 + 5] : NEGF));
    best = fmaxf(best, a4 + fmaxf(Bt[s0 + 4], Bt[s0 + 5]));
    best = fmaxf(best, a5 + fmaxf(fmaxf(Bt[s0 + 5], Bt[s0 + 6]), kb2 ? Bt[s0 + 7] : NEGF));
    best = fmaxf(best, a6 + fmaxf(Bt[s0 + 6], Bt[s0 + 7]));
    best = fmaxf(best, a7 + fmaxf(fmaxf(Bt[s0 + 7], Bt[s0 + 8]), kb3 ? Bt[s0 + 9] : NEGF));
    best = fmaxf(best, a8 + Bt[512]);
    // compensation: C = Sum_{t=0..L-1} blank[t] = LB[2047] + Sum_{i<=L-2} LB[i]
    float csum = 0.f;
#pragma unroll
    for (int i = 0; i < 32; ++i) {
      const int idx = lane + (i << 6);
      csum += (idx <= L - 2) ? LB[idx] : 0.f;
    }
#pragma unroll
    for (int off = 32; off; off >>= 1) {
      best = fmaxf(best, __shfl_down(best, off));
      csum += __shfl_down(csum, off);
    }
    if (lane == 0) vpart[b] = best + csum + LB[2047];
  }
}

// ---------------------------------------------------------------------------
// Kernel C: out = (sum(gpart) - sum(vpart)) / sum(L_b)
// ---------------------------------------------------------------------------
__global__ __launch_bounds__(256) void finalize_kernel(
    const int* __restrict__ llen, const float* __restrict__ gpart,
    const float* __restrict__ vpart, float* __restrict__ out) {
  __shared__ float sred[4], lred[4];
  const int t = threadIdx.x, lane = t & 63, w = t >> 6;
  float s = 0.f;
#pragma unroll
  for (int i = 0; i < 8; ++i) s += gpart[t + (i << 8)];
  float lf = 0.f;
  if (t < 64) { s -= vpart[t]; lf = (float)llen[t]; }
#pragma unroll
  for (int off = 32; off; off >>= 1) {
    s += __shfl_down(s, off);
    lf += __shfl_down(lf, off);
  }
  if (lane == 0) { sred[w] = s; lred[w] = lf; }
  __syncthreads();
  if (t == 0)
    out[0] = (sred[0] + sred[1] + sred[2] + sred[3]) /
             (lred[0] + lred[1] + lred[2] + lred[3]);
}

extern "C" void kernel_launch(void* const* d_in, const int* in_sizes, int n_in,
                              void* d_out, int out_size, void* d_ws, size_t ws_size,
                              hipStream_t stream) {
  const float* logits  = (const float*)d_in[0];   // [B,T,V] fp32
  const int*   targets = (const int*)d_in[1];     // [B,U] int32
  const int*   llen    = (const int*)d_in[2];     // [B]
  const int*   tlen    = (const int*)d_in[3];     // [B]
  float* out = (float*)d_out;

  // ws layout: [0,8K) gpart[2048] | [8K,8K+256) vpart[64] |
  //            [16384, +512K) Ebs fp32 | [1MiB, +64MiB) E2 fp16 quad layout
  float*          gpart = (float*)d_ws;
  float*          vpart = (float*)d_ws + 2048;
  float*          Ebs   = (float*)((char*)d_ws + 16384);
  unsigned short* E     = (unsigned short*)((char*)d_ws + (1u << 20));

  gather_lse_kernel<<<Bb * 32, 256, 0, stream>>>(logits, targets, llen, gpart, Ebs, E);
  viterbi_kernel<<<Bb, 128, 0, stream>>>(E, Ebs, targets, llen, tlen, vpart);
  finalize_kernel<<<1, 256, 0, stream>>>(llen, gpart, vpart, out);
}

// Round 8
// 246.664 us; speedup vs baseline: 1.3791x; 1.0074x over previous
//
#include <hip/hip_runtime.h>

#define NEGF -1e30f
typedef unsigned int uint32;

static constexpr int Bb = 64, Tt = 2048, Vv = 256, Uu = 256;
// S = 2*U+1 = 513 states; lane l owns states 8l..8l+7 (+512 on lane 63).
// R15 = R14 + viterbi slot-shave: (a) explicit v_max3_f32 for label states,
// (b) uniform (SGPR) ring bases + per-lane constant voffsets (scalar bumps).
// Step model: 5 v_max + 4x(cndmask + max3 + fma_mix) + 1 dpp ~= 18 slots;
// cadence ~4.85 cyc/slot (R7/R8/R12/R13 fits) -> ~41 us floor for 1023 steps.

__device__ __forceinline__ unsigned short f2h(float f) {
  return __builtin_bit_cast(unsigned short, (_Float16)f);
}
__device__ __forceinline__ uint32 pk2h_rne(float a, float b) {   // RNE both halves
  return (uint32)f2h(a) | ((uint32)f2h(b) << 16);
}
__device__ __forceinline__ float fp16lo(uint32 w) {
  return (float)__builtin_bit_cast(_Float16, (unsigned short)(w & 0xffffu));
}
__device__ __forceinline__ float fp16hi(uint32 w) {
  return (float)__builtin_bit_cast(_Float16, (unsigned short)(w >> 16));
}
// acc + f32(fp16 half of w): one VOP3P op.
__device__ __forceinline__ float addmix_lo(float acc, uint32 w) {
  float d;
  asm("v_fma_mix_f32 %0, %1, 1.0, %2 op_sel:[0,0,0] op_sel_hi:[1,0,0]"
      : "=v"(d) : "v"(w), "v"(acc));
  return d;
}
__device__ __forceinline__ float addmix_hi(float acc, uint32 w) {
  float d;
  asm("v_fma_mix_f32 %0, %1, 1.0, %2 op_sel:[1,0,0] op_sel_hi:[1,0,0]"
      : "=v"(d) : "v"(w), "v"(acc));
  return d;
}
// three-way max in one VOP3 op (insurance against missed max3 fusion)
__device__ __forceinline__ float max3f(float a, float b, float c) {
  float d;
  asm("v_max3_f32 %0, %1, %2, %3" : "=v"(d) : "v"(a), "v"(b), "v"(c));
  return d;
}

// DPP wave shifts: shr1: lane l <- l-1 (lane0 keeps old); shl1: lane l <- l+1 (lane63 keeps old).
__device__ __forceinline__ float dpp_shr1(float old, float src) {
  return __builtin_bit_cast(float, __builtin_amdgcn_update_dpp(
      __builtin_bit_cast(int, old), __builtin_bit_cast(int, src), 0x138, 0xF, 0xF, false));
}
__device__ __forceinline__ float dpp_shl1(float old, float src) {
  return __builtin_bit_cast(float, __builtin_amdgcn_update_dpp(
      __builtin_bit_cast(int, old), __builtin_bit_cast(int, src), 0x130, 0xF, 0xF, false));
}

// ---------------------------------------------------------------------------
// Kernel A: one streaming pass over logits; wave w handles 8 CONSECUTIVE rows
// tbase..tbase+7 (= 2 aligned quads).  (byte-identical to R14)
// ---------------------------------------------------------------------------
__global__ __launch_bounds__(256) void gather_lse_kernel(
    const float* __restrict__ logits, const int* __restrict__ targets,
    const int* __restrict__ llen, float* __restrict__ gpart,
    float* __restrict__ Ebs, unsigned short* __restrict__ E) {
  __shared__ __align__(16) float buf[4][8][Vv];   // 32 KB
  __shared__ float wpart[4];
  const int b = blockIdx.x >> 5;
  const int c = blockIdx.x & 31;
  const int w = threadIdx.x >> 6;
  const int lane = threadIdx.x & 63;
  const int L = llen[b];
  const int4 lb = reinterpret_cast<const int4*>(targets + (b << 8))[lane];
  const float* __restrict__ lgb = logits + (size_t)b * (Tt * Vv);
  unsigned short* __restrict__ Eb2 = E + ((size_t)b << 19);   // 2^19 ushorts = 1 MiB
  float lse_local = 0.f;
#pragma unroll
  for (int k = 0; k < 2; ++k) {
    const int tbase = (c << 6) + (k << 5) + (w << 3);   // rows tbase..tbase+7
    if (tbase >= L) break;                              // wave-uniform
    float4 v[8];
#pragma unroll
    for (int j = 0; j < 8; ++j)
      v[j] = reinterpret_cast<const float4*>(lgb + (size_t)(tbase + j) * Vv)[lane];
    float s[8];
#pragma unroll
    for (int j = 0; j < 8; ++j)
      s[j] = __expf(v[j].x) + __expf(v[j].y) + __expf(v[j].z) + __expf(v[j].w);
#pragma unroll
    for (int off = 32; off; off >>= 1) {
#pragma unroll
      for (int j = 0; j < 8; ++j) s[j] += __shfl_down(s[j], off);
    }
#pragma unroll
    for (int j = 0; j < 8; ++j)
      reinterpret_cast<float4*>(&buf[w][j][0])[lane] = v[j];
    uint2 u4[4];
#pragma unroll
    for (int j = 0; j < 8; ++j) {                 // intra-wave DS ordering
      const int t = tbase + j;
      const float bl = buf[w][j][0];              // blank of this row (broadcast)
      u4[j & 3] = make_uint2(pk2h_rne(buf[w][j][lb.x] - bl, buf[w][j][lb.y] - bl),
                             pk2h_rne(buf[w][j][lb.z] - bl, buf[w][j][lb.w] - bl));
      if ((j & 3) == 3) {
        if (t - 3 < L) {                          // first row of quad valid
          unsigned short* qptr = Eb2 + (size_t)(t >> 2) * 1024 + (lane << 4);
          *reinterpret_cast<uint4*>(qptr)     = make_uint4(u4[0].x, u4[0].y, u4[1].x, u4[1].y);
          *reinterpret_cast<uint4*>(qptr + 8) = make_uint4(u4[2].x, u4[2].y, u4[3].x, u4[3].y);
        }
      }
      if ((lane == 0) & (t < L)) {
        lse_local += __logf(s[j]);
        Ebs[(b << 11) + ((t == 0) ? 2047 : t - 1)] = v[j].x;   // row[0] = blank
      }
    }
  }
  if (lane == 0) wpart[w] = lse_local;
  __syncthreads();
  if (threadIdx.x == 0)
    gpart[blockIdx.x] = wpart[0] + wpart[1] + wpart[2] + wpart[3];
}

// ---------------------------------------------------------------------------
// Kernel B: bidirectional max-plus Viterbi, 2 waves per batch, potential-
// shifted, quad-grouped fp16 fetch, max3 + scalar-base rings.
// ---------------------------------------------------------------------------
#define PG 8
__global__ __launch_bounds__(128) void viterbi_kernel(
    const unsigned short* __restrict__ E, const float* __restrict__ Ebs,
    const int* __restrict__ targets, const int* __restrict__ llen,
    const int* __restrict__ tlen, float* __restrict__ vpart) {
  __shared__ __align__(16) float LB[2048];   // blanks (shifted layout), 8 KB
  __shared__ float Bt[520];
  const int b = blockIdx.x;
  const int lane = threadIdx.x & 63;
  const int wv = threadIdx.x >> 6;
  const int L = llen[b];
  const int tl = tlen[b];
  const int M = (L - 2) >> 1;
  const int4 lb = reinterpret_cast<const int4*>(targets + (b << 8))[lane];
  const unsigned short* __restrict__ Eb2 = E + ((size_t)b << 19);
  const float* __restrict__ Ebb = Ebs + (b << 11);
  // row r (4 fp16 labels for this lane) in the quad layout:
  auto ldrow = [&](int r) {
    return *reinterpret_cast<const uint2*>(Eb2 + (size_t)(r >> 2) * 1024 + (lane << 4) + ((r & 3) << 2));
  };

  // cooperative blank preload (merge-time compensation only)
  {
    const float4* src = reinterpret_cast<const float4*>(Ebb);
    float4* dst = reinterpret_cast<float4*>(LB);
    for (int i = threadIdx.x; i < 512; i += 128) dst[i] = src[i];
  }
  __syncthreads();

  float a0 = NEGF, a1 = NEGF, a2 = NEGF, a3 = NEGF, a4 = NEGF,
        a5 = NEGF, a6 = NEGF, a7 = NEGF, a8 = NEGF;

  if (wv == 0) {
    // ---------------- forward wave (shifted alpha) ----------------
    const int prevw = __shfl_up(lb.w, 1);
    const bool sk0 = (lane != 0) && (lb.x != prevw);
    const bool sk1 = (lb.y != lb.x);
    const bool sk2 = (lb.z != lb.y);
    const bool sk3 = (lb.w != lb.z);
    if (lane == 0) {
      a0 = 0.f;
      a1 = fp16lo((uint32)Eb2[0]);     // label0 at t=0
    }
    auto stepf = [&](uint32 wx, uint32 wy) {
      const float am1 = dpp_shr1(NEGF, a7);                     // lane0 -> NEGF
      const float x0 = fmaxf(a0, am1);
      const float x1 = addmix_lo(max3f(a1, a0, sk0 ? am1 : NEGF), wx);
      const float x2 = fmaxf(a2, a1);
      const float x3 = addmix_hi(max3f(a3, a2, sk1 ? a1 : NEGF), wx);
      const float x4 = fmaxf(a4, a3);
      const float x5 = addmix_lo(max3f(a5, a4, sk2 ? a3 : NEGF), wy);
      const float x6 = fmaxf(a6, a5);
      const float x7 = addmix_hi(max3f(a7, a6, sk3 ? a5 : NEGF), wy);
      const float x8 = fmaxf(a8, a7);
      a0 = x0; a1 = x1; a2 = x2; a3 = x3; a4 = x4; a5 = x5; a6 = x6; a7 = x7; a8 = x8;
    };
    // ring over aligned quads 1.. (rows 4..M), peel rows 1..3 first.
    // Uniform base (SGPR) + per-lane constant element offsets -> scalar bumps.
    uint4 pf[PG][2];
    const uint4* pqu = reinterpret_cast<const uint4*>(Eb2 + 1024);   // uniform
    const int lo0 = lane << 1, lo1 = (lane << 1) + 1;                // lane offsets
    auto fetchf = [&](int slot) {
      pf[slot][0] = pqu[lo0]; pf[slot][1] = pqu[lo1]; pqu += 128;
    };
#pragma unroll
    for (int s = 0; s < PG; ++s) fetchf(s);
    {   // peel rows 1,2,3 (M >= 511 always)
      const uint2 w1 = ldrow(1), w2 = ldrow(2), w3 = ldrow(3);
      stepf(w1.x, w1.y); stepf(w2.x, w2.y); stepf(w3.x, w3.y);
    }
    __builtin_amdgcn_sched_barrier(0);
    const int n = M - 3, Gf = n >> 2, remf = n & 3;
    int g = 0;
    while (g + PG <= Gf) {
#pragma unroll
      for (int s = 0; s < PG; ++s) {
        stepf(pf[s][0].x, pf[s][0].y);
        stepf(pf[s][0].z, pf[s][0].w);
        stepf(pf[s][1].x, pf[s][1].y);
        stepf(pf[s][1].z, pf[s][1].w);
        fetchf(s);
        __builtin_amdgcn_sched_barrier(0);
      }
      g += PG;
    }
    const int left = Gf - g;   // 0..PG-1
#pragma unroll
    for (int s = 0; s < PG; ++s) {
      if (s < left) {
        stepf(pf[s][0].x, pf[s][0].y);
        stepf(pf[s][0].z, pf[s][0].w);
        stepf(pf[s][1].x, pf[s][1].y);
        stepf(pf[s][1].z, pf[s][1].w);
      }
    }
#pragma unroll
    for (int s = 0; s < PG; ++s) {
      if (s == left) {
        if (remf > 0) stepf(pf[s][0].x, pf[s][0].y);
        if (remf > 1) stepf(pf[s][0].z, pf[s][0].w);
        if (remf > 2) stepf(pf[s][1].x, pf[s][1].y);
      }
    }
  } else {
    // ---------------- backward wave (shifted beta) ----------------
    const int nlabx = __shfl_down(lb.x, 1);
    const bool kb0 = (lb.y != lb.x);
    const bool kb1 = (lb.z != lb.y);
    const bool kb2 = (lb.w != lb.z);
    const bool kb3 = (lane < 63) && (nlabx != lb.w);
    {
      const uint2 er = ldrow(L - 1);
      const float e0 = fp16lo(er.x), e1 = fp16hi(er.x);
      const float e2 = fp16lo(er.y), e3 = fp16hi(er.y);
      const int s0 = 8 * lane, tb = 2 * tl, tm = 2 * tl - 1;
      a0 = (s0     == tb) ? 0.f : NEGF;
      a1 = (s0 + 1 == tm) ? e0  : NEGF;
      a2 = (s0 + 2 == tb) ? 0.f : NEGF;
      a3 = (s0 + 3 == tm) ? e1  : NEGF;
      a4 = (s0 + 4 == tb) ? 0.f : NEGF;
      a5 = (s0 + 5 == tm) ? e2  : NEGF;
      a6 = (s0 + 6 == tb) ? 0.f : NEGF;
      a7 = (s0 + 7 == tm) ? e3  : NEGF;
      a8 = ((lane == 63) && (tb == 512)) ? 0.f : NEGF;
    }
    auto stepb = [&](uint32 wx, uint32 wy) {
      const float bn0 = dpp_shl1(a8, a0);     // lane l: a0[l+1]; lane63: own a8
      const float bn1 = dpp_shl1(NEGF, a1);   // lane l: a1[l+1]; lane63: NEGF
      const float y0 = fmaxf(a0, a1);
      const float y1 = addmix_lo(max3f(a1, a2, kb0 ? a3 : NEGF), wx);
      const float y2 = fmaxf(a2, a3);
      const float y3 = addmix_hi(max3f(a3, a4, kb1 ? a5 : NEGF), wx);
      const float y4 = fmaxf(a4, a5);
      const float y5 = addmix_lo(max3f(a5, a6, kb2 ? a7 : NEGF), wy);
      const float y6 = fmaxf(a6, a7);
      const float y7 = addmix_hi(max3f(a7, bn0, kb3 ? bn1 : NEGF), wy);
      // a8 invariant under the potential shift
      a0 = y0; a1 = y1; a2 = y2; a3 = y3; a4 = y4; a5 = y5; a6 = y6; a7 = y7;
    };
    const int e = L - 2;
    const int p = (e + 1) & 3;     // peel to make next row = 3 (mod 4)
    // ring over aligned quads descending from q0; uniform base, scalar bumps
    uint4 qf[PG][2];
    const int q0 = (e - p) >> 2;
    const uint4* pqu = reinterpret_cast<const uint4*>(Eb2) + ((size_t)q0 << 7);  // uniform
    const int lo0 = lane << 1, lo1 = (lane << 1) + 1;
    auto fetchb = [&](int slot) {
      qf[slot][0] = pqu[lo0]; qf[slot][1] = pqu[lo1]; pqu -= 128;
    };
#pragma unroll
    for (int s = 0; s < PG; ++s) fetchb(s);
    {   // peel rows e, e-1, e-2 as needed (p wave-uniform, 0..3)
      uint2 pw0, pw1, pw2;
      if (p > 0) pw0 = ldrow(e);
      if (p > 1) pw1 = ldrow(e - 1);
      if (p > 2) pw2 = ldrow(e - 2);
      if (p > 0) stepb(pw0.x, pw0.y);
      if (p > 1) stepb(pw1.x, pw1.y);
      if (p > 2) stepb(pw2.x, pw2.y);
    }
    __builtin_amdgcn_sched_barrier(0);
    const int n = (e - M) - p, Gb = n >> 2, remb = n & 3;
    int g = 0;
    while (g + PG <= Gb) {
#pragma unroll
      for (int s = 0; s < PG; ++s) {
        stepb(qf[s][1].z, qf[s][1].w);
        stepb(qf[s][1].x, qf[s][1].y);
        stepb(qf[s][0].z, qf[s][0].w);
        stepb(qf[s][0].x, qf[s][0].y);
        fetchb(s);
        __builtin_amdgcn_sched_barrier(0);
      }
      g += PG;
    }
    const int left = Gb - g;
#pragma unroll
    for (int s = 0; s < PG; ++s) {
      if (s < left) {
        stepb(qf[s][1].z, qf[s][1].w);
        stepb(qf[s][1].x, qf[s][1].y);
        stepb(qf[s][0].z, qf[s][0].w);
        stepb(qf[s][0].x, qf[s][0].y);
      }
    }
#pragma unroll
    for (int s = 0; s < PG; ++s) {
      if (s == left) {
        if (remb > 0) stepb(qf[s][1].z, qf[s][1].w);
        if (remb > 1) stepb(qf[s][1].x, qf[s][1].y);
        if (remb > 2) stepb(qf[s][0].z, qf[s][0].w);
      }
    }
    // dump beta~[M+1] to LDS (+NEG padding)
    Bt[8 * lane + 0] = a0; Bt[8 * lane + 1] = a1;
    Bt[8 * lane + 2] = a2; Bt[8 * lane + 3] = a3;
    Bt[8 * lane + 4] = a4; Bt[8 * lane + 5] = a5;
    Bt[8 * lane + 6] = a6; Bt[8 * lane + 7] = a7;
    if (lane == 63) Bt[512] = a8;
    if (lane == 0) { Bt[513] = NEGF; Bt[514] = NEGF; }
  }
  __syncthreads();
  if (wv == 0) {
    const int nlabx = __shfl_down(lb.x, 1);
    const bool kb0 = (lb.y != lb.x);
    const bool kb1 = (lb.z != lb.y);
    const bool kb2 = (lb.w != lb.z);
    const bool kb3 = (lane < 63) && (nlabx != lb.w);
    const int s0 = 8 * lane;
    float best;
    best =             a0 + fmaxf(Bt[s0],     Bt[s0 + 1]);
    best = fmaxf(best, a1 + fmaxf(fmaxf(Bt[s0 + 1], Bt[s0 + 2]), kb0 ? Bt[s0 + 3] : NEGF));
    best = fmaxf(best, a2 + fmaxf(Bt[s0 + 2], Bt[s0 + 3]));
    best = fmaxf(best, a3 + fmaxf(fmaxf(Bt[s0 + 3], Bt[s0 + 4]), kb1 ? Bt[s0 + 5] : NEGF));
    best = fmaxf(best, a4 + fmaxf(Bt[s0 + 4], Bt[s0 + 5]));
    best = fmaxf(best, a5 + fmaxf(fmaxf(Bt[s0 + 5], Bt[s0 + 6]), kb2 ? Bt[s0 + 7] : NEGF));
    best = fmaxf(best, a6 + fmaxf(Bt[s0 + 6], Bt[s0 + 7]));
    best = fmaxf(best, a7 + fmaxf(fmaxf(Bt[s0 + 7], Bt[s0 + 8]), kb3 ? Bt[s0 + 9] : NEGF));
    best = fmaxf(best, a8 + Bt[512]);
    // compensation: C = Sum_{t=0..L-1} blank[t] = LB[2047] + Sum_{i<=L-2} LB[i]
    float csum = 0.f;
#pragma unroll
    for (int i = 0; i < 32; ++i) {
      const int idx = lane + (i << 6);
      csum += (idx <= L - 2) ? LB[idx] : 0.f;
    }
#pragma unroll
    for (int off = 32; off; off >>= 1) {
      best = fmaxf(best, __shfl_down(best, off));
      csum += __shfl_down(csum, off);
    }
    if (lane == 0) vpart[b] = best + csum + LB[2047];
  }
}

// ---------------------------------------------------------------------------
// Kernel C: out = (sum(gpart) - sum(vpart)) / sum(L_b)
// ---------------------------------------------------------------------------
__global__ __launch_bounds__(256) void finalize_kernel(
    const int* __restrict__ llen, const float* __restrict__ gpart,
    const float* __restrict__ vpart, float* __restrict__ out) {
  __shared__ float sred[4], lred[4];
  const int t = threadIdx.x, lane = t & 63, w = t >> 6;
  float s = 0.f;
#pragma unroll
  for (int i = 0; i < 8; ++i) s += gpart[t + (i << 8)];
  float lf = 0.f;
  if (t < 64) { s -= vpart[t]; lf = (float)llen[t]; }
#pragma unroll
  for (int off = 32; off; off >>= 1) {
    s += __shfl_down(s, off);
    lf += __shfl_down(lf, off);
  }
  if (lane == 0) { sred[w] = s; lred[w] = lf; }
  __syncthreads();
  if (t == 0)
    out[0] = (sred[0] + sred[1] + sred[2] + sred[3]) /
             (lred[0] + lred[1] + lred[2] + lred[3]);
}

extern "C" void kernel_launch(void* const* d_in, const int* in_sizes, int n_in,
                              void* d_out, int out_size, void* d_ws, size_t ws_size,
                              hipStream_t stream) {
  const float* logits  = (const float*)d_in[0];   // [B,T,V] fp32
  const int*   targets = (const int*)d_in[1];     // [B,U] int32
  const int*   llen    = (const int*)d_in[2];     // [B]
  const int*   tlen    = (const int*)d_in[3];     // [B]
  float* out = (float*)d_out;

  // ws layout: [0,8K) gpart[2048] | [8K,8K+256) vpart[64] |
  //            [16384, +512K) Ebs fp32 | [1MiB, +64MiB) E2 fp16 quad layout
  float*          gpart = (float*)d_ws;
  float*          vpart = (float*)d_ws + 2048;
  float*          Ebs   = (float*)((char*)d_ws + 16384);
  unsigned short* E     = (unsigned short*)((char*)d_ws + (1u << 20));

  gather_lse_kernel<<<Bb * 32, 256, 0, stream>>>(logits, targets, llen, gpart, Ebs, E);
  viterbi_kernel<<<Bb, 128, 0, stream>>>(E, Ebs, targets, llen, tlen, vpart);
  finalize_kernel<<<1, 256, 0, stream>>>(llen, gpart, vpart, out);
}